// Round 12
// baseline (277.191 us; speedup 1.0000x reference)
//
#include <hip/hip_runtime.h>
#include <hip/hip_bf16.h>
#include <cstddef>

// FFTformer block. FFTs reduced to 8x8 circular convolutions; conv1x1 GEMMs
// on MFMA (bf16 in, fp32 acc), LN/gate fused into GEMM staging, weights
// pre-converted to padded bf16. FSAS dwconv(q,k)+patch conv via per-row real
// DFT-8; v-dwconv absorbed into the same kernel (NO swizzle: heterogeneous
// blocks rely on round-robin interleave; r7 measured -14us when segregated).
// DFFN: spectral filter as per-channel 64x64 circulant on MFMA with z in
// LDS (As staged in LDS — r10 showed direct-global A-reads expose L2 latency
// on the MFMA chain), fused dwconv3+GELU gate; XCD-bijective swizzle
// (r8: FETCH 127->39MB).  r9: gemm2+gemm3 merged (k_gemm23).
// r11: erff -> A-S 7.1.26 rational erf (|eps|<1.5e-7) in the dffn gate.
// B=2, d=48, H=W=256, P=8.  Workspace (ws_size = 256 MiB):
//   [0,           75,497,472)  QKV bf16 [2,288,HW]  (v; later y)
//   [75,497,472, 150,994,944)  HID bf16 [2,288,HW]
//   [150,994,944,176,160,768)  U   bf16 [2,96,HW]   (out96/u -> g1)
//   [176,160,768,188,743,680)  X1  bf16 [2,48,HW]
//   [188,743,680,201,326,592)  G2  bf16 [2,48,HW]
//   [201,326,592,201,424,896)  WPAD bf16 (awh64 | awo96 | fwi64 | fwo160)
//   [201,424,896,203,784,192)  CMAT bf16 [288][64][64] circulants

constexpr int HWC = 65536;   // 256*256

typedef short short8 __attribute__((ext_vector_type(8)));
typedef __bf16 bf16x8 __attribute__((ext_vector_type(8)));
typedef float f32x4 __attribute__((ext_vector_type(4)));
typedef _Float16 f16x8 __attribute__((ext_vector_type(8)));
typedef _Float16 f16x4 __attribute__((ext_vector_type(4)));

__device__ inline unsigned short f2bf(float f) {
  __hip_bfloat16 h = __float2bfloat16(f);
  return *reinterpret_cast<unsigned short*>(&h);
}
__device__ inline float bf2f(unsigned short u) {
  __hip_bfloat16 h;
  *reinterpret_cast<unsigned short*>(&h) = u;
  return __bfloat162float(h);
}

union V8 { uint4 v; unsigned short us[8]; short s[8]; };

__device__ inline void load8f(const unsigned short* p, float* f) {
  V8 u; u.v = *reinterpret_cast<const uint4*>(p);
#pragma unroll
  for (int j = 0; j < 8; j++) f[j] = bf2f(u.us[j]);
}
__device__ inline void store8bf(unsigned short* p, const float* f) {
  V8 u;
#pragma unroll
  for (int j = 0; j < 8; j++) u.us[j] = f2bf(f[j]);
  *reinterpret_cast<uint4*>(p) = u.v;
}

// Abramowitz-Stegun 7.1.26 erf approximation, |err| <= 1.5e-7 (well below
// bf16 rounding of the gate output).  ~12 VALU ops vs libm erff's ~30.
__device__ inline float erf_fast(float x) {
  float ax = fabsf(x);
  float t = 1.f / (1.f + 0.3275911f * ax);
  float p = t * (0.254829592f +
            t * (-0.284496736f +
            t * (1.421413741f +
            t * (-1.453152027f + t * 1.061405429f))));
  float r = 1.f - p * __expf(-ax * ax);
  return (x < 0.f) ? -r : r;
}

// Real DFT-8 of x[8] -> e = [X0, X1r, X1i, X2r, X2i, X3r, X3i, X4].
__device__ inline void fdft8(const float* x, float* e) {
  const float c = 0.70710678118654752f;
  float t0 = x[0] + x[4], t1 = x[0] - x[4];
  float t2 = x[2] + x[6], t3 = x[2] - x[6];
  float t4 = x[1] + x[5], t5 = x[1] - x[5];
  float t6 = x[3] + x[7], t7 = x[3] - x[7];
  float A = c * (t5 - t7), B = c * (t5 + t7);
  float s1 = t0 + t2, s2 = t4 + t6;
  e[0] = s1 + s2;
  e[7] = s1 - s2;
  e[1] = t1 + A;
  e[5] = t1 - A;
  e[2] = -(B + t3);
  e[6] = t3 - B;
  e[3] = t0 - t2;
  e[4] = t6 - t4;
}

// Inverse DFT-8 of spectrum Z (same bin layout) -> 8 spatial values.
__device__ inline void idft8(const float* Z, float* acc) {
  const float c2 = 0.70710678118654752f;
  float Z0 = Z[0], Z1r = Z[1], Z1i = Z[2], Z2r = Z[3];
  float Z2i = Z[4], Z3r = Z[5], Z3i = Z[6], Z4 = Z[7];
  float u0 = Z0 + Z4, u1 = Z0 - Z4;
  float E = 2.f * Z2r, F = 2.f * (Z1r + Z3r), G = 2.f * (Z1i - Z3i);
  float T = 2.f * Z2i;
  float P = 2.f * c2 * (Z1r - Z1i), Qv = 2.f * c2 * (Z1r + Z1i);
  float R = 2.f * c2 * (Z3r + Z3i), S = 2.f * c2 * (Z3r - Z3i);
  acc[0] = 0.125f * (u0 + E + F);
  acc[4] = 0.125f * (u0 + E - F);
  acc[2] = 0.125f * (u0 - E - G);
  acc[6] = 0.125f * (u0 - E + G);
  acc[1] = 0.125f * (u1 + P - T - R);
  acc[3] = 0.125f * (u1 - Qv + T + S);
  acc[5] = 0.125f * (u1 - P - T + R);
  acc[7] = 0.125f * (u1 + Qv + T - S);
}

__device__ const float c_cos8[8] = {
    1.f, 0.70710678118654752f, 0.f, -0.70710678118654752f,
    -1.f, -0.70710678118654752f, 0.f, 0.70710678118654752f};

// ---------------------------------------------------------------------------
// Pre-convert weights fp32 -> bf16 padded (rows 0..671).  Rows 672..959 build
// CMAT: Cmat[c][m][k] (bf16) 64x64 circulant of s_c = irfft2(ffn_fft[c]).
__global__ __launch_bounds__(64) void k_prep_w(
    const float* __restrict__ awh, const float* __restrict__ awo,
    const float* __restrict__ fwi, const float* __restrict__ fwo,
    const float* __restrict__ fftw, unsigned short* __restrict__ wp,
    unsigned short* __restrict__ cmat) {
  __shared__ float sf[64];
  int row = blockIdx.x, t = threadIdx.x;
  if (row >= 672) {
    int c = row - 672;
    int a = t >> 3, b2 = t & 7;
    const float* W = fftw + c * 40;  // [8][5]
    float acc = 0.f;
    for (int u = 0; u < 8; u++) {
      for (int v = 0; v < 8; v++) {
        float wv;
        if (v <= 4) {
          if (v == 0 || v == 4)
            wv = 0.5f * (W[u * 5 + v] + W[((8 - u) & 7) * 5 + v]);
          else
            wv = W[u * 5 + v];
        } else {
          wv = W[((8 - u) & 7) * 5 + (8 - v)];
        }
        acc += wv * c_cos8[(u * a + v * b2) & 7];
      }
    }
    sf[t] = acc * (1.f / 64.f);
    __syncthreads();
    unsigned short* cp = cmat + (size_t)c * 4096 + t * 64;
    for (int k8 = 0; k8 < 64; k8 += 8) {
      float v[8];
      int ka = k8 >> 3;
      int ia = ((a - ka) & 7) * 8;
#pragma unroll
      for (int j = 0; j < 8; j++) v[j] = sf[ia + ((b2 - j) & 7)];
      store8bf(cp + k8, v);
    }
    return;
  }
  const float* src; int K, KP; unsigned short* dst;
  if (row < 288)      { src = awh + row * 48;        K = 48;  KP = 64;
                        dst = wp + row * 64; }
  else if (row < 336) { int r = row - 288; src = awo + r * 96; K = 96; KP = 96;
                        dst = wp + 18432 + r * 96; }
  else if (row < 624) { int r = row - 336; src = fwi + r * 48; K = 48; KP = 64;
                        dst = wp + 23040 + r * 64; }
  else                { int r = row - 624; src = fwo + r * 144; K = 144; KP = 160;
                        dst = wp + 41472 + r * 160; }
  for (int k = t; k < KP; k += 64) dst[k] = f2bf(k < K ? src[k] : 0.f);
}

// ---------------------------------------------------------------------------
// MFMA GEMM: out[M x N] = Wb[M x KP(bf16)] * X[K x N], 64 px/block.
// XF: 0 none (K split 96/48 s1/s2), 1 LN48 fp32 s1.
// EPI: 0 write bf16[M]; 2 += bf16 res -> fp32.
template <int M, int K, int KP, int XF, int EPI>
__global__ __launch_bounds__(256) void k_gemm(
    const unsigned short* __restrict__ wb, const void* __restrict__ s1,
    const unsigned short* __restrict__ s2, const float* __restrict__ lnw,
    const float* __restrict__ lnb, const void* __restrict__ res,
    void* __restrict__ out) {
  constexpr int STRIDE = KP + 8;
  constexpr int KS = KP / 32;
  constexpr int NT = (M + 63) / 64;
  __shared__ __align__(16) short Xs[64 * STRIDE];   // staging, then epilogue
  __shared__ float redS[4][64], redS2[4][64], mus[64], invs[64];

  int tid = threadIdx.x;
  unsigned bid = blockIdx.x;
  int b = (int)(bid >> 10);
  int hw0 = (int)(bid & 1023) * 64;

  // stage X transposed: Xs[col][k]
  if (XF == 1) {
    const float* xp = (const float*)s1 + (size_t)b * 48 * HWC + hw0;
    for (int idx = tid; idx < 48 * 16; idx += 256) {
      int c = idx >> 4, colg = (idx & 15) * 4;
      float4 f = *reinterpret_cast<const float4*>(xp + (size_t)c * HWC + colg);
      Xs[(colg + 0) * STRIDE + c] = (short)f2bf(f.x);
      Xs[(colg + 1) * STRIDE + c] = (short)f2bf(f.y);
      Xs[(colg + 2) * STRIDE + c] = (short)f2bf(f.z);
      Xs[(colg + 3) * STRIDE + c] = (short)f2bf(f.w);
    }
  } else {
    const unsigned short* p1 =
        (const unsigned short*)s1 + (size_t)b * 96 * HWC + hw0;
    const unsigned short* p2 = s2 + (size_t)b * 48 * HWC + hw0;
    for (int idx = tid; idx < K * 16; idx += 256) {
      int c = idx >> 4, colg = (idx & 15) * 4;
      const unsigned short* p =
          (c < 96) ? (p1 + (size_t)c * HWC + colg)
                   : (p2 + (size_t)(c - 96) * HWC + colg);
      ushort4 uv = *reinterpret_cast<const ushort4*>(p);
      Xs[(colg + 0) * STRIDE + c] = (short)uv.x;
      Xs[(colg + 1) * STRIDE + c] = (short)uv.y;
      Xs[(colg + 2) * STRIDE + c] = (short)uv.z;
      Xs[(colg + 3) * STRIDE + c] = (short)uv.w;
    }
  }

  if constexpr (KP > K) {
    constexpr int PAD = KP - K;
    for (int idx = tid; idx < 64 * PAD; idx += 256) {
      int col = idx / PAD, c = K + (idx % PAD);
      Xs[col * STRIDE + c] = 0;
    }
  }

  if (XF == 1) {
    constexpr int KC = 48;
    __syncthreads();
    {
      int col = tid & 63, q = tid >> 6;
      float s = 0.f, s2 = 0.f;
      for (int c = q * (KC / 4); c < (q + 1) * (KC / 4); c++) {
        float v = bf2f((unsigned short)Xs[col * STRIDE + c]);
        s += v; s2 += v * v;
      }
      redS[q][col] = s; redS2[q][col] = s2;
    }
    __syncthreads();
    if (tid < 64) {
      float ss = redS[0][tid] + redS[1][tid] + redS[2][tid] + redS[3][tid];
      float ss2 = redS2[0][tid] + redS2[1][tid] + redS2[2][tid] + redS2[3][tid];
      float mu = ss * (1.f / KC);
      float var = ss2 * (1.f / KC) - mu * mu;
      mus[tid] = mu; invs[tid] = rsqrtf(var + 1e-5f);
    }
    __syncthreads();
    for (int idx = tid; idx < KC * 64; idx += 256) {
      int c = idx >> 6, col = idx & 63;
      float v = bf2f((unsigned short)Xs[col * STRIDE + c]);
      v = (v - mus[col]) * invs[col] * lnw[c] + lnb[c];
      Xs[col * STRIDE + c] = (short)f2bf(v);
    }
  }
  __syncthreads();

  int lane = tid & 63, wvi = tid >> 6;
  int quad = lane >> 4, mc = lane & 15;
  int kbase = quad * 8;

  short8 bfr[4][KS];
#pragma unroll
  for (int ns = 0; ns < 4; ns++)
#pragma unroll
    for (int ks = 0; ks < KS; ks++)
      bfr[ns][ks] = *reinterpret_cast<const short8*>(
          Xs + (ns * 16 + mc) * STRIDE + ks * 32 + kbase);

  short* Es = Xs;   // epilogue tile [64ch][72]
#pragma unroll
  for (int t = 0; t < NT; t++) {
    int mb = (wvi + 4 * t) * 16;
    f32x4 accs[4];
    if (mb < M) {
      short8 afr[KS];
#pragma unroll
      for (int ks = 0; ks < KS; ks++)
        afr[ks] = *reinterpret_cast<const short8*>(
            wb + (size_t)(mb + mc) * KP + ks * 32 + kbase);
#pragma unroll
      for (int ns = 0; ns < 4; ns++) {
        f32x4 acc = {0.f, 0.f, 0.f, 0.f};
#pragma unroll
        for (int ks = 0; ks < KS; ks++)
          acc = __builtin_amdgcn_mfma_f32_16x16x32_bf16(
              __builtin_bit_cast(bf16x8, afr[ks]),
              __builtin_bit_cast(bf16x8, bfr[ns][ks]), acc, 0, 0, 0);
        accs[ns] = acc;
      }
    }
    __syncthreads();   // Xs free / previous writeback done
    if (mb < M) {
      int chl = wvi * 16 + quad * 4;
#pragma unroll
      for (int ns = 0; ns < 4; ns++)
#pragma unroll
        for (int r = 0; r < 4; r++)
          Es[(chl + r) * 72 + ns * 16 + mc] = (short)f2bf(accs[ns][r]);
    }
    __syncthreads();
#pragma unroll
    for (int i = 0; i < 2; i++) {
      int chl = (tid >> 3) + 32 * i;
      int px0 = (tid & 7) * 8;
      int m = 64 * t + chl;
      if (m < M) {
        V8 ev;
        ev.v = *reinterpret_cast<const uint4*>(Es + chl * 72 + px0);
        size_t off = ((size_t)(b * ((EPI == 0) ? M : 48) + m)) * HWC + hw0 + px0;
        if (EPI == 0) {
          *reinterpret_cast<uint4*>((unsigned short*)out + off) = ev.v;
        } else {
          V8 rv;
          rv.v = *reinterpret_cast<const uint4*>((const unsigned short*)res + off);
          float* op = (float*)out + off;
          float4 oa, ob;
          oa.x = bf2f(rv.us[0]) + bf2f(ev.us[0]);
          oa.y = bf2f(rv.us[1]) + bf2f(ev.us[1]);
          oa.z = bf2f(rv.us[2]) + bf2f(ev.us[2]);
          oa.w = bf2f(rv.us[3]) + bf2f(ev.us[3]);
          ob.x = bf2f(rv.us[4]) + bf2f(ev.us[4]);
          ob.y = bf2f(rv.us[5]) + bf2f(ev.us[5]);
          ob.z = bf2f(rv.us[6]) + bf2f(ev.us[6]);
          ob.w = bf2f(rv.us[7]) + bf2f(ev.us[7]);
          *reinterpret_cast<float4*>(op) = oa;
          *reinterpret_cast<float4*>(op + 4) = ob;
        }
      }
    }
  }
}

// ---------------------------------------------------------------------------
// Merged gemm2+gemm3 (r9 proven): per 64-px tile,
//   x1 = x + W_o * (LN96(u) * v)        [write X1 bf16; keep tile in LDS]
//   y  = W_in * LN48(x1)                [write QKV ch 0..287]
__global__ __launch_bounds__(256) void k_gemm23(
    const unsigned short* __restrict__ wo, const unsigned short* __restrict__ wi,
    const unsigned short* __restrict__ u, unsigned short* __restrict__ qkv,
    const float* __restrict__ anw, const float* __restrict__ anb,
    const float* __restrict__ n2w, const float* __restrict__ n2b,
    const float* __restrict__ x, unsigned short* __restrict__ x1) {
  constexpr int S1 = 104;  // stage1 stride (96+8)
  constexpr int S2 = 72;   // stage2 stride (64+8)
  __shared__ __align__(16) short Xs[64 * S1];   // stage1 u; then Es epilogue
  __shared__ __align__(16) short Vs[64 * S1];   // stage1 v; then x1 [px][ch]
  __shared__ float redS[4][64], redS2[4][64], mus[64], invs[64];

  int tid = threadIdx.x;
  unsigned bid = blockIdx.x;
  int b = (int)(bid >> 10);
  int hw0 = (int)(bid & 1023) * 64;

  // ---- stage1: u + v transposed
  {
    const unsigned short* up = u + (size_t)b * 96 * HWC + hw0;
    const unsigned short* vp = qkv + ((size_t)(b * 288 + 192)) * HWC + hw0;
    for (int idx = tid; idx < 96 * 16; idx += 256) {
      int c = idx >> 4, colg = (idx & 15) * 4;
      ushort4 uv = *reinterpret_cast<const ushort4*>(up + (size_t)c * HWC + colg);
      Xs[(colg + 0) * S1 + c] = (short)uv.x;
      Xs[(colg + 1) * S1 + c] = (short)uv.y;
      Xs[(colg + 2) * S1 + c] = (short)uv.z;
      Xs[(colg + 3) * S1 + c] = (short)uv.w;
      ushort4 vv = *reinterpret_cast<const ushort4*>(vp + (size_t)c * HWC + colg);
      Vs[(colg + 0) * S1 + c] = (short)vv.x;
      Vs[(colg + 1) * S1 + c] = (short)vv.y;
      Vs[(colg + 2) * S1 + c] = (short)vv.z;
      Vs[(colg + 3) * S1 + c] = (short)vv.w;
    }
  }
  // ---- LN96 + v-gate
  __syncthreads();
  {
    int col = tid & 63, q = tid >> 6;
    float s = 0.f, s2 = 0.f;
    for (int c = q * 24; c < (q + 1) * 24; c++) {
      float v = bf2f((unsigned short)Xs[col * S1 + c]);
      s += v; s2 += v * v;
    }
    redS[q][col] = s; redS2[q][col] = s2;
  }
  __syncthreads();
  if (tid < 64) {
    float ss = redS[0][tid] + redS[1][tid] + redS[2][tid] + redS[3][tid];
    float ss2 = redS2[0][tid] + redS2[1][tid] + redS2[2][tid] + redS2[3][tid];
    float mu = ss * (1.f / 96.f);
    float var = ss2 * (1.f / 96.f) - mu * mu;
    mus[tid] = mu; invs[tid] = rsqrtf(var + 1e-5f);
  }
  __syncthreads();
  for (int idx = tid; idx < 96 * 64; idx += 256) {
    int c = idx >> 6, col = idx & 63;
    float v = bf2f((unsigned short)Xs[col * S1 + c]);
    v = (v - mus[col]) * invs[col] * anw[c] + anb[c];
    v *= bf2f((unsigned short)Vs[col * S1 + c]);
    Xs[col * S1 + c] = (short)f2bf(v);
  }
  __syncthreads();

  int lane = tid & 63, wvi = tid >> 6;
  int quad = lane >> 4, mc = lane & 15;
  int kbase = quad * 8;

  // ---- MFMA1: W_o[48x96] (waves 0..2 active)
  short8 bfr1[4][3];
#pragma unroll
  for (int ns = 0; ns < 4; ns++)
#pragma unroll
    for (int ks = 0; ks < 3; ks++)
      bfr1[ns][ks] = *reinterpret_cast<const short8*>(
          Xs + (ns * 16 + mc) * S1 + ks * 32 + kbase);
  bool act1 = (wvi < 3);
  f32x4 acc1[4];
  if (act1) {
    int mb = wvi * 16;
    short8 afr[3];
#pragma unroll
    for (int ks = 0; ks < 3; ks++)
      afr[ks] = *reinterpret_cast<const short8*>(
          wo + (size_t)(mb + mc) * 96 + ks * 32 + kbase);
#pragma unroll
    for (int ns = 0; ns < 4; ns++) {
      f32x4 acc = {0.f, 0.f, 0.f, 0.f};
#pragma unroll
      for (int ks = 0; ks < 3; ks++)
        acc = __builtin_amdgcn_mfma_f32_16x16x32_bf16(
            __builtin_bit_cast(bf16x8, afr[ks]),
            __builtin_bit_cast(bf16x8, bfr1[ns][ks]), acc, 0, 0, 0);
      acc1[ns] = acc;
    }
  }
  __syncthreads();   // everyone done reading Xs/Vs stage1 data
  // ---- x1 tile (acc + residual) into Vs as [px][ch], stride S2
  if (act1) {
    int chl = wvi * 16 + quad * 4;
#pragma unroll
    for (int ns = 0; ns < 4; ns++) {
      int px = ns * 16 + mc;
#pragma unroll
      for (int r = 0; r < 4; r++) {
        int m = chl + r;
        float xr = x[((size_t)(b * 48 + m)) * HWC + hw0 + px];
        Vs[px * S2 + m] = (short)f2bf(acc1[ns][r] + xr);
      }
    }
  }
  // zero-pad ch 48..63 (KP2=64)
  for (int idx = tid; idx < 64 * 16; idx += 256) {
    int col = idx >> 4, c = 48 + (idx & 15);
    Vs[col * S2 + c] = 0;
  }
  __syncthreads();
  // ---- coop X1 HBM write (bf16 [ch][px]) + LN48 stats (both read-only)
  for (int u2 = tid; u2 < 48 * 8; u2 += 256) {
    int m = u2 >> 3, px0 = (u2 & 7) * 8;
    V8 pk;
#pragma unroll
    for (int j = 0; j < 8; j++)
      pk.us[j] = (unsigned short)Vs[(px0 + j) * S2 + m];
    *reinterpret_cast<uint4*>(x1 + ((size_t)(b * 48 + m)) * HWC + hw0 + px0) =
        pk.v;
  }
  {
    int col = tid & 63, q = tid >> 6;
    float s = 0.f, s2 = 0.f;
    for (int c = q * 12; c < (q + 1) * 12; c++) {
      float v = bf2f((unsigned short)Vs[col * S2 + c]);
      s += v; s2 += v * v;
    }
    redS[q][col] = s; redS2[q][col] = s2;
  }
  __syncthreads();
  if (tid < 64) {
    float ss = redS[0][tid] + redS[1][tid] + redS[2][tid] + redS[3][tid];
    float ss2 = redS2[0][tid] + redS2[1][tid] + redS2[2][tid] + redS2[3][tid];
    float mu = ss * (1.f / 48.f);
    float var = ss2 * (1.f / 48.f) - mu * mu;
    mus[tid] = mu; invs[tid] = rsqrtf(var + 1e-5f);
  }
  __syncthreads();
  for (int idx = tid; idx < 48 * 64; idx += 256) {
    int c = idx >> 6, col = idx & 63;
    float v = bf2f((unsigned short)Vs[col * S2 + c]);
    v = (v - mus[col]) * invs[col] * n2w[c] + n2b[c];
    Vs[col * S2 + c] = (short)f2bf(v);
  }
  __syncthreads();

  // ---- MFMA2: W_in[288x64(pad)] x LN48(x1) -> y (QKV ch 0..287)
  short8 bfr2[4][2];
#pragma unroll
  for (int ns = 0; ns < 4; ns++)
#pragma unroll
    for (int ks = 0; ks < 2; ks++)
      bfr2[ns][ks] = *reinterpret_cast<const short8*>(
          Vs + (ns * 16 + mc) * S2 + ks * 32 + kbase);
  short* Es = Xs;
#pragma unroll
  for (int t = 0; t < 5; t++) {
    int mb = (wvi + 4 * t) * 16;
    f32x4 accs[4];
    if (mb < 288) {
      short8 afr[2];
#pragma unroll
      for (int ks = 0; ks < 2; ks++)
        afr[ks] = *reinterpret_cast<const short8*>(
            wi + (size_t)(mb + mc) * 64 + ks * 32 + kbase);
#pragma unroll
      for (int ns = 0; ns < 4; ns++) {
        f32x4 acc = {0.f, 0.f, 0.f, 0.f};
#pragma unroll
        for (int ks = 0; ks < 2; ks++)
          acc = __builtin_amdgcn_mfma_f32_16x16x32_bf16(
              __builtin_bit_cast(bf16x8, afr[ks]),
              __builtin_bit_cast(bf16x8, bfr2[ns][ks]), acc, 0, 0, 0);
        accs[ns] = acc;
      }
    }
    __syncthreads();
    if (mb < 288) {
      int chl = wvi * 16 + quad * 4;
#pragma unroll
      for (int ns = 0; ns < 4; ns++)
#pragma unroll
        for (int r = 0; r < 4; r++)
          Es[(chl + r) * 72 + ns * 16 + mc] = (short)f2bf(accs[ns][r]);
    }
    __syncthreads();
#pragma unroll
    for (int i = 0; i < 2; i++) {
      int chl = (tid >> 3) + 32 * i;
      int px0 = (tid & 7) * 8;
      int m = 64 * t + chl;
      if (m < 288) {
        V8 ev;
        ev.v = *reinterpret_cast<const uint4*>(Es + chl * 72 + px0);
        *reinterpret_cast<uint4*>(
            qkv + ((size_t)(b * 288 + m)) * HWC + hw0 + px0) = ev.v;
      }
    }
  }
}

// ---------------------------------------------------------------------------
// FSAS fused + v-dwconv.  cc<96: dwconv3(q,k) on the fly, per-row DFT-8,
// freq-domain circular conv, idft8.  cc>=96: v dwconv3.  NO blockIdx swizzle.
__global__ __launch_bounds__(256) void k_fsas_fused(
    const unsigned short* __restrict__ hid, const float* __restrict__ dw,
    unsigned short* __restrict__ out, unsigned short* __restrict__ qkv) {
  constexpr int LSTR = 260;            // f32/row: 256 + 4 pad
  __shared__ __align__(16) float qs[8 * LSTR];
  __shared__ __align__(16) float kt[8 * LSTR];
  int tid = threadIdx.x;
  unsigned bid = blockIdx.x;                 // b*192*32 + cc*32 + py
  int py = (int)(bid & 31);
  unsigned t = bid >> 5;
  int cc = (int)(t % 192u);
  int b = (int)(t / 192u);
  int r = tid >> 5, seg = tid & 31, lane = tid & 63;

  if (cc >= 96) {
    int c = 96 + cc;                         // 192..287
    const unsigned short* ip = hid + ((size_t)(b * 288 + c)) * HWC;
    float wv[9];
#pragma unroll
    for (int k = 0; k < 9; k++) wv[k] = dw[c * 9 + k];
    int y = py * 8 + r;
    float f[3][8];
#pragma unroll
    for (int dy = 0; dy < 3; dy++) {
      int yy = y + dy - 1;
      if (yy >= 0 && yy < 256) {
        load8f(ip + yy * 256 + seg * 8, f[dy]);
      } else {
#pragma unroll
        for (int j = 0; j < 8; j++) f[dy][j] = 0.f;
      }
    }
    float o[8];
#pragma unroll
    for (int dy = 0; dy < 3; dy++) {
      float lv = __shfl(f[dy][7], lane - 1, 64);
      float rv = __shfl(f[dy][0], lane + 1, 64);
      if (seg == 0) lv = 0.f;
      if (seg == 31) rv = 0.f;
#pragma unroll
      for (int j = 0; j < 8; j++) {
        float xl = (j == 0) ? lv : f[dy][j - 1];
        float xr = (j == 7) ? rv : f[dy][j + 1];
        float v = xl * wv[dy * 3] + f[dy][j] * wv[dy * 3 + 1] + xr * wv[dy * 3 + 2];
        o[j] = (dy == 0) ? v : o[j] + v;
      }
    }
    store8bf(qkv + ((size_t)(b * 288 + c)) * HWC + y * 256 + seg * 8, o);
    return;
  }

  int c = cc;
  const unsigned short* qp = hid + ((size_t)(b * 288 + c)) * HWC;
  const unsigned short* kp = hid + ((size_t)(b * 288 + 96 + c)) * HWC;
  float w1[9], w2[9];
#pragma unroll
  for (int k = 0; k < 9; k++) {
    w1[k] = dw[c * 9 + k];
    w2[k] = dw[(96 + c) * 9 + k];
  }
  int y = py * 8 + r;
  float f1[3][8], f2[3][8];
#pragma unroll
  for (int dy = 0; dy < 3; dy++) {
    int yy = y + dy - 1;
    if (yy >= 0 && yy < 256) {
      load8f(qp + yy * 256 + seg * 8, f1[dy]);
      load8f(kp + yy * 256 + seg * 8, f2[dy]);
    } else {
#pragma unroll
      for (int j = 0; j < 8; j++) { f1[dy][j] = 0.f; f2[dy][j] = 0.f; }
    }
  }
  float d1[8], d2[8];
#pragma unroll
  for (int j = 0; j < 8; j++) { d1[j] = 0.f; d2[j] = 0.f; }
#pragma unroll
  for (int dy = 0; dy < 3; dy++) {
    float lv1 = __shfl(f1[dy][7], lane - 1, 64);
    float rv1 = __shfl(f1[dy][0], lane + 1, 64);
    float lv2 = __shfl(f2[dy][7], lane - 1, 64);
    float rv2 = __shfl(f2[dy][0], lane + 1, 64);
    if (seg == 0) { lv1 = 0.f; lv2 = 0.f; }
    if (seg == 31) { rv1 = 0.f; rv2 = 0.f; }
#pragma unroll
    for (int j = 0; j < 8; j++) {
      float xl1 = (j == 0) ? lv1 : f1[dy][j - 1];
      float xr1 = (j == 7) ? rv1 : f1[dy][j + 1];
      float xl2 = (j == 0) ? lv2 : f2[dy][j - 1];
      float xr2 = (j == 7) ? rv2 : f2[dy][j + 1];
      d1[j] += xl1 * w1[dy * 3] + f1[dy][j] * w1[dy * 3 + 1] + xr1 * w1[dy * 3 + 2];
      d2[j] += xl2 * w2[dy * 3] + f2[dy][j] * w2[dy * 3 + 1] + xr2 * w2[dy * 3 + 2];
    }
  }
  {
    float e1[8], e2[8];
    fdft8(d1, e1);
    fdft8(d2, e2);
    float4 a1 = {e1[0], e1[1], e1[2], e1[3]};
    float4 b1 = {e1[4], e1[5], e1[6], e1[7]};
    float4 a2 = {e2[0], e2[1], e2[2], e2[3]};
    float4 b2 = {e2[4], e2[5], e2[6], e2[7]};
    *reinterpret_cast<float4*>(&qs[r * LSTR + seg * 8]) = a1;
    *reinterpret_cast<float4*>(&qs[r * LSTR + seg * 8 + 4]) = b1;
    *reinterpret_cast<float4*>(&kt[r * LSTR + seg * 8]) = a2;
    *reinterpret_cast<float4*>(&kt[r * LSTR + seg * 8 + 4]) = b2;
  }
  __syncthreads();
  int p = tid >> 3, a = tid & 7;
  float Z[8];
#pragma unroll
  for (int j = 0; j < 8; j++) Z[j] = 0.f;
#pragma unroll
  for (int i = 0; i < 8; i++) {
    float4 qa = *reinterpret_cast<const float4*>(&qs[i * LSTR + p * 8]);
    float4 qb = *reinterpret_cast<const float4*>(&qs[i * LSTR + p * 8 + 4]);
    int ar = (a - i) & 7;
    float4 ka = *reinterpret_cast<const float4*>(&kt[ar * LSTR + p * 8]);
    float4 kb = *reinterpret_cast<const float4*>(&kt[ar * LSTR + p * 8 + 4]);
    Z[0] += qa.x * ka.x;
    Z[7] += qb.w * kb.w;
    Z[1] += qa.y * ka.y - qa.z * ka.z;
    Z[2] += qa.y * ka.z + qa.z * ka.y;
    Z[3] += qa.w * ka.w - qb.x * kb.x;
    Z[4] += qa.w * kb.x + qb.x * ka.w;
    Z[5] += qb.y * kb.y - qb.z * kb.z;
    Z[6] += qb.y * kb.z + qb.z * kb.y;
  }
  float acc[8];
  idft8(Z, acc);
  store8bf(out + ((size_t)(b * 96 + c)) * HWC + (py * 8 + a) * 256 + p * 8,
           acc);
}

// ---------------------------------------------------------------------------
// DFFN fused on MFMA (r9 structure: As staged in LDS — r10's direct-global
// A-reads exposed L2 latency on the MFMA chain): per channel pair
// (cg, cg+144), slab py: z = C_c * y per patch via 64x32 circulant MFMA +
// halo MFMAs, z in LDS, then dwconv3 + fast-erf GELU gate.  XCD-bijective
// swizzle (r8: FETCH 127->39MB).
__global__ __launch_bounds__(256) void k_dffn_mfma(
    const unsigned short* __restrict__ y, const unsigned short* __restrict__ cmat,
    const float* __restrict__ dwf, unsigned short* __restrict__ g1,
    unsigned short* __restrict__ g2) {
  constexpr int ZSTR = 264;
  __shared__ __align__(16) short As[64 * 72];
  __shared__ __align__(16) short Bs3[3][32 * 72];
  __shared__ __align__(16) _Float16 zb[2][10 * ZSTR];
  int tid = threadIdx.x;
  unsigned hw = blockIdx.x;                  // nwg = 2*144*32 = 9216
  unsigned bid = (hw & 7u) * 1152u + (hw >> 3);
  int py = (int)(bid & 31);
  int cg = (int)((bid >> 5) % 144u);
  int b  = (int)((bid >> 5) / 144u);
  int y0 = py * 8;
  int lane = tid & 63, wvi = tid >> 6;
  int quad = lane >> 4, mc = lane & 15;
  int kbase = quad * 8;

#pragma unroll
  for (int h = 0; h < 2; h++) {
    int c = cg + h * 144;
    const unsigned short* yp = y + ((size_t)(b * 288 + c)) * HWC;
    __syncthreads();   // As/Bs3 readers of previous h done
    {
      const unsigned short* cp = cmat + (size_t)c * 4096;
      int m = tid >> 2, kq = (tid & 3) * 16;
      *reinterpret_cast<uint4*>(As + m * 72 + kq) =
          *reinterpret_cast<const uint4*>(cp + m * 64 + kq);
      *reinterpret_cast<uint4*>(As + m * 72 + kq + 8) =
          *reinterpret_cast<const uint4*>(cp + m * 64 + kq + 8);
    }
    {
      int rr = tid >> 5, seg = tid & 31;
#pragma unroll
      for (int s = 0; s < 3; s++) {
        int slab = py - 1 + s;
        uint4 v = {0u, 0u, 0u, 0u};
        if (slab >= 0 && slab < 32)
          v = *reinterpret_cast<const uint4*>(yp + slab * 2048 + rr * 256 +
                                              seg * 8);
        *reinterpret_cast<uint4*>(&Bs3[s][seg * 72 + rr * 8]) = v;
      }
    }
    __syncthreads();
    // center slab: 64x32, 4 waves x 2 n-halves (proven patchconv core)
    {
      short8 afr[2];
#pragma unroll
      for (int ks = 0; ks < 2; ks++)
        afr[ks] = *reinterpret_cast<const short8*>(
            As + (wvi * 16 + mc) * 72 + ks * 32 + kbase);
#pragma unroll
      for (int nt = 0; nt < 2; nt++) {
        f32x4 acc = {0.f, 0.f, 0.f, 0.f};
#pragma unroll
        for (int ks = 0; ks < 2; ks++) {
          short8 bfr = *reinterpret_cast<const short8*>(
              &Bs3[1][(nt * 16 + mc) * 72 + ks * 32 + kbase]);
          acc = __builtin_amdgcn_mfma_f32_16x16x32_bf16(
              __builtin_bit_cast(bf16x8, afr[ks]),
              __builtin_bit_cast(bf16x8, bfr), acc, 0, 0, 0);
        }
        int p = nt * 16 + mc;
        int m0 = wvi * 16 + quad * 4;
        int a = m0 >> 3, b8 = m0 & 7;
        f16x4 z4;
#pragma unroll
        for (int r = 0; r < 4; r++) z4[r] = (_Float16)acc[r];
        *reinterpret_cast<f16x4*>(&zb[h][(1 + a) * ZSTR + p * 8 + b8]) = z4;
      }
    }
    // halo: wave -> (hb = wvi&1: 0 top/zb0, 1 bottom/zb9; nth = wvi>>1).
    // top: C rows 56..63 x B(py-1) -> z row 7 of those patches = image y0-1.
    // bottom: C rows 0..7 x B(py+1) -> z row 0 = image y0+8.  A rows use
    // (mc&7) duplication so all reads in-bounds; D rows m>=8 discarded.
    {
      int hb = wvi & 1, nth = wvi >> 1;
      int arow = (hb == 0) ? (56 + (mc & 7)) : (mc & 7);
      const short* Bn = &Bs3[(hb == 0) ? 0 : 2][0];
      f32x4 acc = {0.f, 0.f, 0.f, 0.f};
#pragma unroll
      for (int ks = 0; ks < 2; ks++) {
        short8 afr = *reinterpret_cast<const short8*>(
            As + arow * 72 + ks * 32 + kbase);
        short8 bfr = *reinterpret_cast<const short8*>(
            Bn + (nth * 16 + mc) * 72 + ks * 32 + kbase);
        acc = __builtin_amdgcn_mfma_f32_16x16x32_bf16(
            __builtin_bit_cast(bf16x8, afr),
            __builtin_bit_cast(bf16x8, bfr), acc, 0, 0, 0);
      }
      if (quad < 2) {
        int p = nth * 16 + mc;
        int m0 = quad * 4;              // col within patch row (0..7)
        f16x4 z4;
#pragma unroll
        for (int r = 0; r < 4; r++) z4[r] = (_Float16)acc[r];
        *reinterpret_cast<f16x4*>(
            &zb[h][(hb ? 9 : 0) * ZSTR + p * 8 + m0]) = z4;
      }
    }
  }
  __syncthreads();
  // gate phase: dual dwconv3 + fast-erf GELU
  int r = tid >> 5, seg = tid & 31;
  float w1[9], w2[9];
#pragma unroll
  for (int k = 0; k < 9; k++) {
    w1[k] = dwf[cg * 9 + k];
    w2[k] = dwf[(144 + cg) * 9 + k];
  }
  float d1[8], d2[8];
#pragma unroll
  for (int j = 0; j < 8; j++) { d1[j] = 0.f; d2[j] = 0.f; }
#pragma unroll
  for (int dy = 0; dy < 3; dy++) {
    int zr = r + dy;                        // zb row = image row y0+r-1+dy
    {
      const _Float16* z = &zb[0][zr * ZSTR];
      f16x8 cv = *reinterpret_cast<const f16x8*>(&z[seg * 8]);
      float lv = (seg == 0) ? 0.f : (float)z[seg * 8 - 1];
      float rv = (seg == 31) ? 0.f : (float)z[seg * 8 + 8];
#pragma unroll
      for (int j = 0; j < 8; j++) {
        float xl = (j == 0) ? lv : (float)cv[j - 1];
        float xr = (j == 7) ? rv : (float)cv[j + 1];
        d1[j] += xl * w1[dy * 3] + (float)cv[j] * w1[dy * 3 + 1] + xr * w1[dy * 3 + 2];
      }
    }
    {
      const _Float16* z = &zb[1][zr * ZSTR];
      f16x8 cv = *reinterpret_cast<const f16x8*>(&z[seg * 8]);
      float lv = (seg == 0) ? 0.f : (float)z[seg * 8 - 1];
      float rv = (seg == 31) ? 0.f : (float)z[seg * 8 + 8];
#pragma unroll
      for (int j = 0; j < 8; j++) {
        float xl = (j == 0) ? lv : (float)cv[j - 1];
        float xr = (j == 7) ? rv : (float)cv[j + 1];
        d2[j] += xl * w2[dy * 3] + (float)cv[j] * w2[dy * 3 + 1] + xr * w2[dy * 3 + 2];
      }
    }
  }
  float o[8];
#pragma unroll
  for (int j = 0; j < 8; j++)
    o[j] = 0.5f * d1[j] *
           (1.f + erf_fast(d1[j] * 0.70710678118654752f)) * d2[j];
  unsigned short* gp = (cg < 96)
      ? g1 + ((size_t)(b * 96 + cg)) * HWC
      : g2 + ((size_t)(b * 48 + (cg - 96))) * HWC;
  store8bf(gp + (y0 + r) * 256 + seg * 8, o);
}

// ---------------------------------------------------------------------------
extern "C" void kernel_launch(void* const* d_in, const int* in_sizes, int n_in,
                              void* d_out, int out_size, void* d_ws,
                              size_t ws_size, hipStream_t stream) {
  (void)in_sizes; (void)n_in; (void)out_size; (void)ws_size;
  const float* x   = (const float*)d_in[0];
  const float* n1w = (const float*)d_in[1];
  const float* n1b = (const float*)d_in[2];
  const float* awh = (const float*)d_in[3];   // [288,48]
  const float* adw = (const float*)d_in[4];   // [288,1,3,3]
  const float* anw = (const float*)d_in[5];   // [96]
  const float* anb = (const float*)d_in[6];
  const float* awo = (const float*)d_in[7];   // [48,96]
  const float* n2w = (const float*)d_in[8];
  const float* n2b = (const float*)d_in[9];
  const float* fwi = (const float*)d_in[10];  // [288,48]
  const float* fff = (const float*)d_in[11];  // [288,1,1,8,5]
  const float* fdw = (const float*)d_in[12];  // [288,1,3,3]
  const float* fwo = (const float*)d_in[13];  // [48,144]

  unsigned short* QKV  = (unsigned short*)d_ws;                       // 75.5 MB
  unsigned short* HID  = (unsigned short*)((char*)d_ws + 75497472);   // 75.5 MB
  unsigned short* U    = (unsigned short*)((char*)d_ws + 150994944);  // 25.2 MB
  unsigned short* X1   = (unsigned short*)((char*)d_ws + 176160768);  // 12.6 MB
  unsigned short* G2   = (unsigned short*)((char*)d_ws + 188743680);  // 12.6 MB
  unsigned short* WP   = (unsigned short*)((char*)d_ws + 201326592);  // 96 KB
  unsigned short* CMAT = (unsigned short*)((char*)d_ws + 201424896);  // 2.36 MB
  unsigned short* WA = WP;             // awh padded [288][64]
  unsigned short* WO = WP + 18432;     // awo [48][96]
  unsigned short* WI = WP + 23040;     // fwi padded [288][64]
  unsigned short* WF = WP + 41472;     // fwo padded [48][160]

  k_prep_w<<<960, 64, 0, stream>>>(awh, awo, fwi, fwo, fff, WP, CMAT);
  // FSAS: hidden = W_h * LN1(x)  [LN fused]
  k_gemm<288, 48, 64, 1, 0><<<2048, 256, 0, stream>>>(WA, x, nullptr, n1w,
                                                      n1b, nullptr, HID);
  // q,k fused patch conv -> U ; v dwconv -> QKV (merged kernel)
  k_fsas_fused<<<2 * 192 * 32, 256, 0, stream>>>(HID, adw, U, QKV);
  // x1 = x + W_o*(LN(u)*v); y = W_in*LN(x1)  [merged, x1 tile in LDS]
  k_gemm23<<<2048, 256, 0, stream>>>(WO, WI, U, QKV, anw, anb, n2w, n2b, x,
                                     X1);
  // spectral filter (MFMA circulant, z in LDS) + dwconv + GELU gate
  k_dffn_mfma<<<2 * 144 * 32, 256, 0, stream>>>(QKV, CMAT, fdw, U, G2);
  // out = x1 + W_out * g  (g split U/G2), fp32 output
  k_gemm<48, 144, 160, 0, 2><<<2048, 256, 0, stream>>>(WF, U, G2, nullptr,
                                                       nullptr, X1,
                                                       (float*)d_out);
}

// Round 13
// 273.092 us; speedup vs baseline: 1.0150x; 1.0150x over previous
//
#include <hip/hip_runtime.h>
#include <hip/hip_bf16.h>
#include <cstddef>

// FFTformer block. FFTs reduced to 8x8 circular convolutions; conv1x1 GEMMs
// on MFMA (bf16 in, fp32 acc), LN/gate fused into GEMM staging, weights
// pre-converted to padded bf16. FSAS dwconv(q,k)+patch conv via per-row real
// DFT-8; v-dwconv absorbed into the same kernel (NO swizzle: heterogeneous
// blocks rely on round-robin interleave; r7 measured -14us when segregated).
// DFFN: spectral filter as per-channel 64x64 circulant on MFMA with z in
// LDS (As staged in LDS — r10: direct-global A-reads expose L2 latency),
// fused dwconv3 + libm-erff GELU gate (r12: A-S rational erf REGRESSED —
// rcp+exp transcendental chain slower than erff's polynomial); XCD-bijective
// swizzle (r8: FETCH 127->39MB).  r9: gemm2+gemm3 merged (k_gemm23).
// r13: epilogue Es ping-pong in k_gemm (NT>1) and k_gemm23 MFMA2 — halves
// in-loop barriers (write Es[t&1]; bar; read — t+2 overwrite ordered by the
// t+1 barrier).
// B=2, d=48, H=W=256, P=8.  Workspace (ws_size = 256 MiB):
//   [0,           75,497,472)  QKV bf16 [2,288,HW]  (v; later y)
//   [75,497,472, 150,994,944)  HID bf16 [2,288,HW]
//   [150,994,944,176,160,768)  U   bf16 [2,96,HW]   (out96/u -> g1)
//   [176,160,768,188,743,680)  X1  bf16 [2,48,HW]
//   [188,743,680,201,326,592)  G2  bf16 [2,48,HW]
//   [201,326,592,201,424,896)  WPAD bf16 (awh64 | awo96 | fwi64 | fwo160)
//   [201,424,896,203,784,192)  CMAT bf16 [288][64][64] circulants

constexpr int HWC = 65536;   // 256*256

typedef short short8 __attribute__((ext_vector_type(8)));
typedef __bf16 bf16x8 __attribute__((ext_vector_type(8)));
typedef float f32x4 __attribute__((ext_vector_type(4)));
typedef _Float16 f16x8 __attribute__((ext_vector_type(8)));
typedef _Float16 f16x4 __attribute__((ext_vector_type(4)));

__device__ inline unsigned short f2bf(float f) {
  __hip_bfloat16 h = __float2bfloat16(f);
  return *reinterpret_cast<unsigned short*>(&h);
}
__device__ inline float bf2f(unsigned short u) {
  __hip_bfloat16 h;
  *reinterpret_cast<unsigned short*>(&h) = u;
  return __bfloat162float(h);
}

union V8 { uint4 v; unsigned short us[8]; short s[8]; };

__device__ inline void load8f(const unsigned short* p, float* f) {
  V8 u; u.v = *reinterpret_cast<const uint4*>(p);
#pragma unroll
  for (int j = 0; j < 8; j++) f[j] = bf2f(u.us[j]);
}
__device__ inline void store8bf(unsigned short* p, const float* f) {
  V8 u;
#pragma unroll
  for (int j = 0; j < 8; j++) u.us[j] = f2bf(f[j]);
  *reinterpret_cast<uint4*>(p) = u.v;
}

// Real DFT-8 of x[8] -> e = [X0, X1r, X1i, X2r, X2i, X3r, X3i, X4].
__device__ inline void fdft8(const float* x, float* e) {
  const float c = 0.70710678118654752f;
  float t0 = x[0] + x[4], t1 = x[0] - x[4];
  float t2 = x[2] + x[6], t3 = x[2] - x[6];
  float t4 = x[1] + x[5], t5 = x[1] - x[5];
  float t6 = x[3] + x[7], t7 = x[3] - x[7];
  float A = c * (t5 - t7), B = c * (t5 + t7);
  float s1 = t0 + t2, s2 = t4 + t6;
  e[0] = s1 + s2;
  e[7] = s1 - s2;
  e[1] = t1 + A;
  e[5] = t1 - A;
  e[2] = -(B + t3);
  e[6] = t3 - B;
  e[3] = t0 - t2;
  e[4] = t6 - t4;
}

// Inverse DFT-8 of spectrum Z (same bin layout) -> 8 spatial values.
__device__ inline void idft8(const float* Z, float* acc) {
  const float c2 = 0.70710678118654752f;
  float Z0 = Z[0], Z1r = Z[1], Z1i = Z[2], Z2r = Z[3];
  float Z2i = Z[4], Z3r = Z[5], Z3i = Z[6], Z4 = Z[7];
  float u0 = Z0 + Z4, u1 = Z0 - Z4;
  float E = 2.f * Z2r, F = 2.f * (Z1r + Z3r), G = 2.f * (Z1i - Z3i);
  float T = 2.f * Z2i;
  float P = 2.f * c2 * (Z1r - Z1i), Qv = 2.f * c2 * (Z1r + Z1i);
  float R = 2.f * c2 * (Z3r + Z3i), S = 2.f * c2 * (Z3r - Z3i);
  acc[0] = 0.125f * (u0 + E + F);
  acc[4] = 0.125f * (u0 + E - F);
  acc[2] = 0.125f * (u0 - E - G);
  acc[6] = 0.125f * (u0 - E + G);
  acc[1] = 0.125f * (u1 + P - T - R);
  acc[3] = 0.125f * (u1 - Qv + T + S);
  acc[5] = 0.125f * (u1 - P - T + R);
  acc[7] = 0.125f * (u1 + Qv + T - S);
}

__device__ const float c_cos8[8] = {
    1.f, 0.70710678118654752f, 0.f, -0.70710678118654752f,
    -1.f, -0.70710678118654752f, 0.f, 0.70710678118654752f};

// ---------------------------------------------------------------------------
// Pre-convert weights fp32 -> bf16 padded (rows 0..671).  Rows 672..959 build
// CMAT: Cmat[c][m][k] (bf16) 64x64 circulant of s_c = irfft2(ffn_fft[c]).
__global__ __launch_bounds__(64) void k_prep_w(
    const float* __restrict__ awh, const float* __restrict__ awo,
    const float* __restrict__ fwi, const float* __restrict__ fwo,
    const float* __restrict__ fftw, unsigned short* __restrict__ wp,
    unsigned short* __restrict__ cmat) {
  __shared__ float sf[64];
  int row = blockIdx.x, t = threadIdx.x;
  if (row >= 672) {
    int c = row - 672;
    int a = t >> 3, b2 = t & 7;
    const float* W = fftw + c * 40;  // [8][5]
    float acc = 0.f;
    for (int u = 0; u < 8; u++) {
      for (int v = 0; v < 8; v++) {
        float wv;
        if (v <= 4) {
          if (v == 0 || v == 4)
            wv = 0.5f * (W[u * 5 + v] + W[((8 - u) & 7) * 5 + v]);
          else
            wv = W[u * 5 + v];
        } else {
          wv = W[((8 - u) & 7) * 5 + (8 - v)];
        }
        acc += wv * c_cos8[(u * a + v * b2) & 7];
      }
    }
    sf[t] = acc * (1.f / 64.f);
    __syncthreads();
    unsigned short* cp = cmat + (size_t)c * 4096 + t * 64;
    for (int k8 = 0; k8 < 64; k8 += 8) {
      float v[8];
      int ka = k8 >> 3;
      int ia = ((a - ka) & 7) * 8;
#pragma unroll
      for (int j = 0; j < 8; j++) v[j] = sf[ia + ((b2 - j) & 7)];
      store8bf(cp + k8, v);
    }
    return;
  }
  const float* src; int K, KP; unsigned short* dst;
  if (row < 288)      { src = awh + row * 48;        K = 48;  KP = 64;
                        dst = wp + row * 64; }
  else if (row < 336) { int r = row - 288; src = awo + r * 96; K = 96; KP = 96;
                        dst = wp + 18432 + r * 96; }
  else if (row < 624) { int r = row - 336; src = fwi + r * 48; K = 48; KP = 64;
                        dst = wp + 23040 + r * 64; }
  else                { int r = row - 624; src = fwo + r * 144; K = 144; KP = 160;
                        dst = wp + 41472 + r * 160; }
  for (int k = t; k < KP; k += 64) dst[k] = f2bf(k < K ? src[k] : 0.f);
}

// ---------------------------------------------------------------------------
// MFMA GEMM: out[M x N] = Wb[M x KP(bf16)] * X[K x N], 64 px/block.
// XF: 0 none (K split 96/48 s1/s2), 1 LN48 fp32 s1.
// EPI: 0 write bf16[M]; 2 += bf16 res -> fp32.
// r13: Es ping-pong (Xs / Es2) -> one barrier per t instead of two.
template <int M, int K, int KP, int XF, int EPI>
__global__ __launch_bounds__(256) void k_gemm(
    const unsigned short* __restrict__ wb, const void* __restrict__ s1,
    const unsigned short* __restrict__ s2, const float* __restrict__ lnw,
    const float* __restrict__ lnb, const void* __restrict__ res,
    void* __restrict__ out) {
  constexpr int STRIDE = KP + 8;
  constexpr int KS = KP / 32;
  constexpr int NT = (M + 63) / 64;
  __shared__ __align__(16) short Xs[64 * STRIDE];   // staging, then epilogue A
  __shared__ __align__(16) short Es2[(NT > 1) ? 64 * 72 : 4];  // epilogue B
  __shared__ float redS[4][64], redS2[4][64], mus[64], invs[64];

  int tid = threadIdx.x;
  unsigned bid = blockIdx.x;
  int b = (int)(bid >> 10);
  int hw0 = (int)(bid & 1023) * 64;

  // stage X transposed: Xs[col][k]
  if (XF == 1) {
    const float* xp = (const float*)s1 + (size_t)b * 48 * HWC + hw0;
    for (int idx = tid; idx < 48 * 16; idx += 256) {
      int c = idx >> 4, colg = (idx & 15) * 4;
      float4 f = *reinterpret_cast<const float4*>(xp + (size_t)c * HWC + colg);
      Xs[(colg + 0) * STRIDE + c] = (short)f2bf(f.x);
      Xs[(colg + 1) * STRIDE + c] = (short)f2bf(f.y);
      Xs[(colg + 2) * STRIDE + c] = (short)f2bf(f.z);
      Xs[(colg + 3) * STRIDE + c] = (short)f2bf(f.w);
    }
  } else {
    const unsigned short* p1 =
        (const unsigned short*)s1 + (size_t)b * 96 * HWC + hw0;
    const unsigned short* p2 = s2 + (size_t)b * 48 * HWC + hw0;
    for (int idx = tid; idx < K * 16; idx += 256) {
      int c = idx >> 4, colg = (idx & 15) * 4;
      const unsigned short* p =
          (c < 96) ? (p1 + (size_t)c * HWC + colg)
                   : (p2 + (size_t)(c - 96) * HWC + colg);
      ushort4 uv = *reinterpret_cast<const ushort4*>(p);
      Xs[(colg + 0) * STRIDE + c] = (short)uv.x;
      Xs[(colg + 1) * STRIDE + c] = (short)uv.y;
      Xs[(colg + 2) * STRIDE + c] = (short)uv.z;
      Xs[(colg + 3) * STRIDE + c] = (short)uv.w;
    }
  }

  if constexpr (KP > K) {
    constexpr int PAD = KP - K;
    for (int idx = tid; idx < 64 * PAD; idx += 256) {
      int col = idx / PAD, c = K + (idx % PAD);
      Xs[col * STRIDE + c] = 0;
    }
  }

  if (XF == 1) {
    constexpr int KC = 48;
    __syncthreads();
    {
      int col = tid & 63, q = tid >> 6;
      float s = 0.f, s2 = 0.f;
      for (int c = q * (KC / 4); c < (q + 1) * (KC / 4); c++) {
        float v = bf2f((unsigned short)Xs[col * STRIDE + c]);
        s += v; s2 += v * v;
      }
      redS[q][col] = s; redS2[q][col] = s2;
    }
    __syncthreads();
    if (tid < 64) {
      float ss = redS[0][tid] + redS[1][tid] + redS[2][tid] + redS[3][tid];
      float ss2 = redS2[0][tid] + redS2[1][tid] + redS2[2][tid] + redS2[3][tid];
      float mu = ss * (1.f / KC);
      float var = ss2 * (1.f / KC) - mu * mu;
      mus[tid] = mu; invs[tid] = rsqrtf(var + 1e-5f);
    }
    __syncthreads();
    for (int idx = tid; idx < KC * 64; idx += 256) {
      int c = idx >> 6, col = idx & 63;
      float v = bf2f((unsigned short)Xs[col * STRIDE + c]);
      v = (v - mus[col]) * invs[col] * lnw[c] + lnb[c];
      Xs[col * STRIDE + c] = (short)f2bf(v);
    }
  }
  __syncthreads();

  int lane = tid & 63, wvi = tid >> 6;
  int quad = lane >> 4, mc = lane & 15;
  int kbase = quad * 8;

  short8 bfr[4][KS];
#pragma unroll
  for (int ns = 0; ns < 4; ns++)
#pragma unroll
    for (int ks = 0; ks < KS; ks++)
      bfr[ns][ks] = *reinterpret_cast<const short8*>(
          Xs + (ns * 16 + mc) * STRIDE + ks * 32 + kbase);

  __syncthreads();   // all bfr loads done; Xs reusable as epilogue buffer
#pragma unroll
  for (int t = 0; t < NT; t++) {
    int mb = (wvi + 4 * t) * 16;
    f32x4 accs[4];
    if (mb < M) {
      short8 afr[KS];
#pragma unroll
      for (int ks = 0; ks < KS; ks++)
        afr[ks] = *reinterpret_cast<const short8*>(
            wb + (size_t)(mb + mc) * KP + ks * 32 + kbase);
#pragma unroll
      for (int ns = 0; ns < 4; ns++) {
        f32x4 acc = {0.f, 0.f, 0.f, 0.f};
#pragma unroll
        for (int ks = 0; ks < KS; ks++)
          acc = __builtin_amdgcn_mfma_f32_16x16x32_bf16(
              __builtin_bit_cast(bf16x8, afr[ks]),
              __builtin_bit_cast(bf16x8, bfr[ns][ks]), acc, 0, 0, 0);
        accs[ns] = acc;
      }
    }
    short* Est = (NT > 1 && (t & 1)) ? Es2 : Xs;   // ping-pong
    if (mb < M) {
      int chl = wvi * 16 + quad * 4;
#pragma unroll
      for (int ns = 0; ns < 4; ns++)
#pragma unroll
        for (int r = 0; r < 4; r++)
          Est[(chl + r) * 72 + ns * 16 + mc] = (short)f2bf(accs[ns][r]);
    }
    __syncthreads();
#pragma unroll
    for (int i = 0; i < 2; i++) {
      int chl = (tid >> 3) + 32 * i;
      int px0 = (tid & 7) * 8;
      int m = 64 * t + chl;
      if (m < M) {
        V8 ev;
        ev.v = *reinterpret_cast<const uint4*>(Est + chl * 72 + px0);
        size_t off = ((size_t)(b * ((EPI == 0) ? M : 48) + m)) * HWC + hw0 + px0;
        if (EPI == 0) {
          *reinterpret_cast<uint4*>((unsigned short*)out + off) = ev.v;
        } else {
          V8 rv;
          rv.v = *reinterpret_cast<const uint4*>((const unsigned short*)res + off);
          float* op = (float*)out + off;
          float4 oa, ob;
          oa.x = bf2f(rv.us[0]) + bf2f(ev.us[0]);
          oa.y = bf2f(rv.us[1]) + bf2f(ev.us[1]);
          oa.z = bf2f(rv.us[2]) + bf2f(ev.us[2]);
          oa.w = bf2f(rv.us[3]) + bf2f(ev.us[3]);
          ob.x = bf2f(rv.us[4]) + bf2f(ev.us[4]);
          ob.y = bf2f(rv.us[5]) + bf2f(ev.us[5]);
          ob.z = bf2f(rv.us[6]) + bf2f(ev.us[6]);
          ob.w = bf2f(rv.us[7]) + bf2f(ev.us[7]);
          *reinterpret_cast<float4*>(op) = oa;
          *reinterpret_cast<float4*>(op + 4) = ob;
        }
      }
    }
  }
}

// ---------------------------------------------------------------------------
// Merged gemm2+gemm3 (r9 proven): per 64-px tile,
//   x1 = x + W_o * (LN96(u) * v)        [write X1 bf16; keep tile in LDS]
//   y  = W_in * LN48(x1)                [write QKV ch 0..287]
// r13: MFMA2 epilogue ping-pongs Xs/Vs (Vs free once bfr2 is in registers).
__global__ __launch_bounds__(256) void k_gemm23(
    const unsigned short* __restrict__ wo, const unsigned short* __restrict__ wi,
    const unsigned short* __restrict__ u, unsigned short* __restrict__ qkv,
    const float* __restrict__ anw, const float* __restrict__ anb,
    const float* __restrict__ n2w, const float* __restrict__ n2b,
    const float* __restrict__ x, unsigned short* __restrict__ x1) {
  constexpr int S1 = 104;  // stage1 stride (96+8)
  constexpr int S2 = 72;   // stage2 stride (64+8)
  __shared__ __align__(16) short Xs[64 * S1];   // stage1 u; then epilogue A
  __shared__ __align__(16) short Vs[64 * S1];   // stage1 v; x1; epilogue B
  __shared__ float redS[4][64], redS2[4][64], mus[64], invs[64];

  int tid = threadIdx.x;
  unsigned bid = blockIdx.x;
  int b = (int)(bid >> 10);
  int hw0 = (int)(bid & 1023) * 64;

  // ---- stage1: u + v transposed
  {
    const unsigned short* up = u + (size_t)b * 96 * HWC + hw0;
    const unsigned short* vp = qkv + ((size_t)(b * 288 + 192)) * HWC + hw0;
    for (int idx = tid; idx < 96 * 16; idx += 256) {
      int c = idx >> 4, colg = (idx & 15) * 4;
      ushort4 uv = *reinterpret_cast<const ushort4*>(up + (size_t)c * HWC + colg);
      Xs[(colg + 0) * S1 + c] = (short)uv.x;
      Xs[(colg + 1) * S1 + c] = (short)uv.y;
      Xs[(colg + 2) * S1 + c] = (short)uv.z;
      Xs[(colg + 3) * S1 + c] = (short)uv.w;
      ushort4 vv = *reinterpret_cast<const ushort4*>(vp + (size_t)c * HWC + colg);
      Vs[(colg + 0) * S1 + c] = (short)vv.x;
      Vs[(colg + 1) * S1 + c] = (short)vv.y;
      Vs[(colg + 2) * S1 + c] = (short)vv.z;
      Vs[(colg + 3) * S1 + c] = (short)vv.w;
    }
  }
  // ---- LN96 + v-gate
  __syncthreads();
  {
    int col = tid & 63, q = tid >> 6;
    float s = 0.f, s2 = 0.f;
    for (int c = q * 24; c < (q + 1) * 24; c++) {
      float v = bf2f((unsigned short)Xs[col * S1 + c]);
      s += v; s2 += v * v;
    }
    redS[q][col] = s; redS2[q][col] = s2;
  }
  __syncthreads();
  if (tid < 64) {
    float ss = redS[0][tid] + redS[1][tid] + redS[2][tid] + redS[3][tid];
    float ss2 = redS2[0][tid] + redS2[1][tid] + redS2[2][tid] + redS2[3][tid];
    float mu = ss * (1.f / 96.f);
    float var = ss2 * (1.f / 96.f) - mu * mu;
    mus[tid] = mu; invs[tid] = rsqrtf(var + 1e-5f);
  }
  __syncthreads();
  for (int idx = tid; idx < 96 * 64; idx += 256) {
    int c = idx >> 6, col = idx & 63;
    float v = bf2f((unsigned short)Xs[col * S1 + c]);
    v = (v - mus[col]) * invs[col] * anw[c] + anb[c];
    v *= bf2f((unsigned short)Vs[col * S1 + c]);
    Xs[col * S1 + c] = (short)f2bf(v);
  }
  __syncthreads();

  int lane = tid & 63, wvi = tid >> 6;
  int quad = lane >> 4, mc = lane & 15;
  int kbase = quad * 8;

  // ---- MFMA1: W_o[48x96] (waves 0..2 active)
  short8 bfr1[4][3];
#pragma unroll
  for (int ns = 0; ns < 4; ns++)
#pragma unroll
    for (int ks = 0; ks < 3; ks++)
      bfr1[ns][ks] = *reinterpret_cast<const short8*>(
          Xs + (ns * 16 + mc) * S1 + ks * 32 + kbase);
  bool act1 = (wvi < 3);
  f32x4 acc1[4];
  if (act1) {
    int mb = wvi * 16;
    short8 afr[3];
#pragma unroll
    for (int ks = 0; ks < 3; ks++)
      afr[ks] = *reinterpret_cast<const short8*>(
          wo + (size_t)(mb + mc) * 96 + ks * 32 + kbase);
#pragma unroll
    for (int ns = 0; ns < 4; ns++) {
      f32x4 acc = {0.f, 0.f, 0.f, 0.f};
#pragma unroll
      for (int ks = 0; ks < 3; ks++)
        acc = __builtin_amdgcn_mfma_f32_16x16x32_bf16(
            __builtin_bit_cast(bf16x8, afr[ks]),
            __builtin_bit_cast(bf16x8, bfr1[ns][ks]), acc, 0, 0, 0);
      acc1[ns] = acc;
    }
  }
  __syncthreads();   // everyone done reading Xs/Vs stage1 data
  // ---- x1 tile (acc + residual) into Vs as [px][ch], stride S2
  if (act1) {
    int chl = wvi * 16 + quad * 4;
#pragma unroll
    for (int ns = 0; ns < 4; ns++) {
      int px = ns * 16 + mc;
#pragma unroll
      for (int r = 0; r < 4; r++) {
        int m = chl + r;
        float xr = x[((size_t)(b * 48 + m)) * HWC + hw0 + px];
        Vs[px * S2 + m] = (short)f2bf(acc1[ns][r] + xr);
      }
    }
  }
  // zero-pad ch 48..63 (KP2=64)
  for (int idx = tid; idx < 64 * 16; idx += 256) {
    int col = idx >> 4, c = 48 + (idx & 15);
    Vs[col * S2 + c] = 0;
  }
  __syncthreads();
  // ---- coop X1 HBM write (bf16 [ch][px]) + LN48 stats (both read-only)
  for (int u2 = tid; u2 < 48 * 8; u2 += 256) {
    int m = u2 >> 3, px0 = (u2 & 7) * 8;
    V8 pk;
#pragma unroll
    for (int j = 0; j < 8; j++)
      pk.us[j] = (unsigned short)Vs[(px0 + j) * S2 + m];
    *reinterpret_cast<uint4*>(x1 + ((size_t)(b * 48 + m)) * HWC + hw0 + px0) =
        pk.v;
  }
  {
    int col = tid & 63, q = tid >> 6;
    float s = 0.f, s2 = 0.f;
    for (int c = q * 12; c < (q + 1) * 12; c++) {
      float v = bf2f((unsigned short)Vs[col * S2 + c]);
      s += v; s2 += v * v;
    }
    redS[q][col] = s; redS2[q][col] = s2;
  }
  __syncthreads();
  if (tid < 64) {
    float ss = redS[0][tid] + redS[1][tid] + redS[2][tid] + redS[3][tid];
    float ss2 = redS2[0][tid] + redS2[1][tid] + redS2[2][tid] + redS2[3][tid];
    float mu = ss * (1.f / 48.f);
    float var = ss2 * (1.f / 48.f) - mu * mu;
    mus[tid] = mu; invs[tid] = rsqrtf(var + 1e-5f);
  }
  __syncthreads();
  for (int idx = tid; idx < 48 * 64; idx += 256) {
    int c = idx >> 6, col = idx & 63;
    float v = bf2f((unsigned short)Vs[col * S2 + c]);
    v = (v - mus[col]) * invs[col] * n2w[c] + n2b[c];
    Vs[col * S2 + c] = (short)f2bf(v);
  }
  __syncthreads();

  // ---- MFMA2: W_in[288x64(pad)] x LN48(x1) -> y (QKV ch 0..287)
  short8 bfr2[4][2];
#pragma unroll
  for (int ns = 0; ns < 4; ns++)
#pragma unroll
    for (int ks = 0; ks < 2; ks++)
      bfr2[ns][ks] = *reinterpret_cast<const short8*>(
          Vs + (ns * 16 + mc) * S2 + ks * 32 + kbase);
  __syncthreads();   // all bfr2 loads done; Xs/Vs reusable as epilogue buffers
#pragma unroll
  for (int t = 0; t < 5; t++) {
    int mb = (wvi + 4 * t) * 16;
    f32x4 accs[4];
    if (mb < 288) {
      short8 afr[2];
#pragma unroll
      for (int ks = 0; ks < 2; ks++)
        afr[ks] = *reinterpret_cast<const short8*>(
            wi + (size_t)(mb + mc) * 64 + ks * 32 + kbase);
#pragma unroll
      for (int ns = 0; ns < 4; ns++) {
        f32x4 acc = {0.f, 0.f, 0.f, 0.f};
#pragma unroll
        for (int ks = 0; ks < 2; ks++)
          acc = __builtin_amdgcn_mfma_f32_16x16x32_bf16(
              __builtin_bit_cast(bf16x8, afr[ks]),
              __builtin_bit_cast(bf16x8, bfr2[ns][ks]), acc, 0, 0, 0);
        accs[ns] = acc;
      }
    }
    short* Est = (t & 1) ? Vs : Xs;   // ping-pong
    if (mb < 288) {
      int chl = wvi * 16 + quad * 4;
#pragma unroll
      for (int ns = 0; ns < 4; ns++)
#pragma unroll
        for (int r = 0; r < 4; r++)
          Est[(chl + r) * 72 + ns * 16 + mc] = (short)f2bf(accs[ns][r]);
    }
    __syncthreads();
#pragma unroll
    for (int i = 0; i < 2; i++) {
      int chl = (tid >> 3) + 32 * i;
      int px0 = (tid & 7) * 8;
      int m = 64 * t + chl;
      if (m < 288) {
        V8 ev;
        ev.v = *reinterpret_cast<const uint4*>(Est + chl * 72 + px0);
        *reinterpret_cast<uint4*>(
            qkv + ((size_t)(b * 288 + m)) * HWC + hw0 + px0) = ev.v;
      }
    }
  }
}

// ---------------------------------------------------------------------------
// FSAS fused + v-dwconv.  cc<96: dwconv3(q,k) on the fly, per-row DFT-8,
// freq-domain circular conv, idft8.  cc>=96: v dwconv3.  NO blockIdx swizzle.
__global__ __launch_bounds__(256) void k_fsas_fused(
    const unsigned short* __restrict__ hid, const float* __restrict__ dw,
    unsigned short* __restrict__ out, unsigned short* __restrict__ qkv) {
  constexpr int LSTR = 260;            // f32/row: 256 + 4 pad
  __shared__ __align__(16) float qs[8 * LSTR];
  __shared__ __align__(16) float kt[8 * LSTR];
  int tid = threadIdx.x;
  unsigned bid = blockIdx.x;                 // b*192*32 + cc*32 + py
  int py = (int)(bid & 31);
  unsigned t = bid >> 5;
  int cc = (int)(t % 192u);
  int b = (int)(t / 192u);
  int r = tid >> 5, seg = tid & 31, lane = tid & 63;

  if (cc >= 96) {
    int c = 96 + cc;                         // 192..287
    const unsigned short* ip = hid + ((size_t)(b * 288 + c)) * HWC;
    float wv[9];
#pragma unroll
    for (int k = 0; k < 9; k++) wv[k] = dw[c * 9 + k];
    int y = py * 8 + r;
    float f[3][8];
#pragma unroll
    for (int dy = 0; dy < 3; dy++) {
      int yy = y + dy - 1;
      if (yy >= 0 && yy < 256) {
        load8f(ip + yy * 256 + seg * 8, f[dy]);
      } else {
#pragma unroll
        for (int j = 0; j < 8; j++) f[dy][j] = 0.f;
      }
    }
    float o[8];
#pragma unroll
    for (int dy = 0; dy < 3; dy++) {
      float lv = __shfl(f[dy][7], lane - 1, 64);
      float rv = __shfl(f[dy][0], lane + 1, 64);
      if (seg == 0) lv = 0.f;
      if (seg == 31) rv = 0.f;
#pragma unroll
      for (int j = 0; j < 8; j++) {
        float xl = (j == 0) ? lv : f[dy][j - 1];
        float xr = (j == 7) ? rv : f[dy][j + 1];
        float v = xl * wv[dy * 3] + f[dy][j] * wv[dy * 3 + 1] + xr * wv[dy * 3 + 2];
        o[j] = (dy == 0) ? v : o[j] + v;
      }
    }
    store8bf(qkv + ((size_t)(b * 288 + c)) * HWC + y * 256 + seg * 8, o);
    return;
  }

  int c = cc;
  const unsigned short* qp = hid + ((size_t)(b * 288 + c)) * HWC;
  const unsigned short* kp = hid + ((size_t)(b * 288 + 96 + c)) * HWC;
  float w1[9], w2[9];
#pragma unroll
  for (int k = 0; k < 9; k++) {
    w1[k] = dw[c * 9 + k];
    w2[k] = dw[(96 + c) * 9 + k];
  }
  int y = py * 8 + r;
  float f1[3][8], f2[3][8];
#pragma unroll
  for (int dy = 0; dy < 3; dy++) {
    int yy = y + dy - 1;
    if (yy >= 0 && yy < 256) {
      load8f(qp + yy * 256 + seg * 8, f1[dy]);
      load8f(kp + yy * 256 + seg * 8, f2[dy]);
    } else {
#pragma unroll
      for (int j = 0; j < 8; j++) { f1[dy][j] = 0.f; f2[dy][j] = 0.f; }
    }
  }
  float d1[8], d2[8];
#pragma unroll
  for (int j = 0; j < 8; j++) { d1[j] = 0.f; d2[j] = 0.f; }
#pragma unroll
  for (int dy = 0; dy < 3; dy++) {
    float lv1 = __shfl(f1[dy][7], lane - 1, 64);
    float rv1 = __shfl(f1[dy][0], lane + 1, 64);
    float lv2 = __shfl(f2[dy][7], lane - 1, 64);
    float rv2 = __shfl(f2[dy][0], lane + 1, 64);
    if (seg == 0) { lv1 = 0.f; lv2 = 0.f; }
    if (seg == 31) { rv1 = 0.f; rv2 = 0.f; }
#pragma unroll
    for (int j = 0; j < 8; j++) {
      float xl1 = (j == 0) ? lv1 : f1[dy][j - 1];
      float xr1 = (j == 7) ? rv1 : f1[dy][j + 1];
      float xl2 = (j == 0) ? lv2 : f2[dy][j - 1];
      float xr2 = (j == 7) ? rv2 : f2[dy][j + 1];
      d1[j] += xl1 * w1[dy * 3] + f1[dy][j] * w1[dy * 3 + 1] + xr1 * w1[dy * 3 + 2];
      d2[j] += xl2 * w2[dy * 3] + f2[dy][j] * w2[dy * 3 + 1] + xr2 * w2[dy * 3 + 2];
    }
  }
  {
    float e1[8], e2[8];
    fdft8(d1, e1);
    fdft8(d2, e2);
    float4 a1 = {e1[0], e1[1], e1[2], e1[3]};
    float4 b1 = {e1[4], e1[5], e1[6], e1[7]};
    float4 a2 = {e2[0], e2[1], e2[2], e2[3]};
    float4 b2 = {e2[4], e2[5], e2[6], e2[7]};
    *reinterpret_cast<float4*>(&qs[r * LSTR + seg * 8]) = a1;
    *reinterpret_cast<float4*>(&qs[r * LSTR + seg * 8 + 4]) = b1;
    *reinterpret_cast<float4*>(&kt[r * LSTR + seg * 8]) = a2;
    *reinterpret_cast<float4*>(&kt[r * LSTR + seg * 8 + 4]) = b2;
  }
  __syncthreads();
  int p = tid >> 3, a = tid & 7;
  float Z[8];
#pragma unroll
  for (int j = 0; j < 8; j++) Z[j] = 0.f;
#pragma unroll
  for (int i = 0; i < 8; i++) {
    float4 qa = *reinterpret_cast<const float4*>(&qs[i * LSTR + p * 8]);
    float4 qb = *reinterpret_cast<const float4*>(&qs[i * LSTR + p * 8 + 4]);
    int ar = (a - i) & 7;
    float4 ka = *reinterpret_cast<const float4*>(&kt[ar * LSTR + p * 8]);
    float4 kb = *reinterpret_cast<const float4*>(&kt[ar * LSTR + p * 8 + 4]);
    Z[0] += qa.x * ka.x;
    Z[7] += qb.w * kb.w;
    Z[1] += qa.y * ka.y - qa.z * ka.z;
    Z[2] += qa.y * ka.z + qa.z * ka.y;
    Z[3] += qa.w * ka.w - qb.x * kb.x;
    Z[4] += qa.w * kb.x + qb.x * ka.w;
    Z[5] += qb.y * kb.y - qb.z * kb.z;
    Z[6] += qb.y * kb.z + qb.z * kb.y;
  }
  float acc[8];
  idft8(Z, acc);
  store8bf(out + ((size_t)(b * 96 + c)) * HWC + (py * 8 + a) * 256 + p * 8,
           acc);
}

// ---------------------------------------------------------------------------
// DFFN fused on MFMA (r9 structure: As staged in LDS): per channel pair
// (cg, cg+144), slab py: z = C_c * y per patch via 64x32 circulant MFMA +
// halo MFMAs, z in LDS, then dwconv3 + erff GELU gate (r12: fast-erf
// regressed).  XCD-bijective swizzle (r8: FETCH 127->39MB).
__global__ __launch_bounds__(256) void k_dffn_mfma(
    const unsigned short* __restrict__ y, const unsigned short* __restrict__ cmat,
    const float* __restrict__ dwf, unsigned short* __restrict__ g1,
    unsigned short* __restrict__ g2) {
  constexpr int ZSTR = 264;
  __shared__ __align__(16) short As[64 * 72];
  __shared__ __align__(16) short Bs3[3][32 * 72];
  __shared__ __align__(16) _Float16 zb[2][10 * ZSTR];
  int tid = threadIdx.x;
  unsigned hw = blockIdx.x;                  // nwg = 2*144*32 = 9216
  unsigned bid = (hw & 7u) * 1152u + (hw >> 3);
  int py = (int)(bid & 31);
  int cg = (int)((bid >> 5) % 144u);
  int b  = (int)((bid >> 5) / 144u);
  int y0 = py * 8;
  int lane = tid & 63, wvi = tid >> 6;
  int quad = lane >> 4, mc = lane & 15;
  int kbase = quad * 8;

#pragma unroll
  for (int h = 0; h < 2; h++) {
    int c = cg + h * 144;
    const unsigned short* yp = y + ((size_t)(b * 288 + c)) * HWC;
    __syncthreads();   // As/Bs3 readers of previous h done
    {
      const unsigned short* cp = cmat + (size_t)c * 4096;
      int m = tid >> 2, kq = (tid & 3) * 16;
      *reinterpret_cast<uint4*>(As + m * 72 + kq) =
          *reinterpret_cast<const uint4*>(cp + m * 64 + kq);
      *reinterpret_cast<uint4*>(As + m * 72 + kq + 8) =
          *reinterpret_cast<const uint4*>(cp + m * 64 + kq + 8);
    }
    {
      int rr = tid >> 5, seg = tid & 31;
#pragma unroll
      for (int s = 0; s < 3; s++) {
        int slab = py - 1 + s;
        uint4 v = {0u, 0u, 0u, 0u};
        if (slab >= 0 && slab < 32)
          v = *reinterpret_cast<const uint4*>(yp + slab * 2048 + rr * 256 +
                                              seg * 8);
        *reinterpret_cast<uint4*>(&Bs3[s][seg * 72 + rr * 8]) = v;
      }
    }
    __syncthreads();
    // center slab: 64x32, 4 waves x 2 n-halves (proven patchconv core)
    {
      short8 afr[2];
#pragma unroll
      for (int ks = 0; ks < 2; ks++)
        afr[ks] = *reinterpret_cast<const short8*>(
            As + (wvi * 16 + mc) * 72 + ks * 32 + kbase);
#pragma unroll
      for (int nt = 0; nt < 2; nt++) {
        f32x4 acc = {0.f, 0.f, 0.f, 0.f};
#pragma unroll
        for (int ks = 0; ks < 2; ks++) {
          short8 bfr = *reinterpret_cast<const short8*>(
              &Bs3[1][(nt * 16 + mc) * 72 + ks * 32 + kbase]);
          acc = __builtin_amdgcn_mfma_f32_16x16x32_bf16(
              __builtin_bit_cast(bf16x8, afr[ks]),
              __builtin_bit_cast(bf16x8, bfr), acc, 0, 0, 0);
        }
        int p = nt * 16 + mc;
        int m0 = wvi * 16 + quad * 4;
        int a = m0 >> 3, b8 = m0 & 7;
        f16x4 z4;
#pragma unroll
        for (int r = 0; r < 4; r++) z4[r] = (_Float16)acc[r];
        *reinterpret_cast<f16x4*>(&zb[h][(1 + a) * ZSTR + p * 8 + b8]) = z4;
      }
    }
    // halo: wave -> (hb = wvi&1: 0 top/zb0, 1 bottom/zb9; nth = wvi>>1).
    // top: C rows 56..63 x B(py-1) -> z row 7 of those patches = image y0-1.
    // bottom: C rows 0..7 x B(py+1) -> z row 0 = image y0+8.  A rows use
    // (mc&7) duplication so all reads in-bounds; D rows m>=8 discarded.
    {
      int hb = wvi & 1, nth = wvi >> 1;
      int arow = (hb == 0) ? (56 + (mc & 7)) : (mc & 7);
      const short* Bn = &Bs3[(hb == 0) ? 0 : 2][0];
      f32x4 acc = {0.f, 0.f, 0.f, 0.f};
#pragma unroll
      for (int ks = 0; ks < 2; ks++) {
        short8 afr = *reinterpret_cast<const short8*>(
            As + arow * 72 + ks * 32 + kbase);
        short8 bfr = *reinterpret_cast<const short8*>(
            Bn + (nth * 16 + mc) * 72 + ks * 32 + kbase);
        acc = __builtin_amdgcn_mfma_f32_16x16x32_bf16(
            __builtin_bit_cast(bf16x8, afr),
            __builtin_bit_cast(bf16x8, bfr), acc, 0, 0, 0);
      }
      if (quad < 2) {
        int p = nth * 16 + mc;
        int m0 = quad * 4;              // col within patch row (0..7)
        f16x4 z4;
#pragma unroll
        for (int r = 0; r < 4; r++) z4[r] = (_Float16)acc[r];
        *reinterpret_cast<f16x4*>(
            &zb[h][(hb ? 9 : 0) * ZSTR + p * 8 + m0]) = z4;
      }
    }
  }
  __syncthreads();
  // gate phase: dual dwconv3 + exact GELU (erff)
  int r = tid >> 5, seg = tid & 31;
  float w1[9], w2[9];
#pragma unroll
  for (int k = 0; k < 9; k++) {
    w1[k] = dwf[cg * 9 + k];
    w2[k] = dwf[(144 + cg) * 9 + k];
  }
  float d1[8], d2[8];
#pragma unroll
  for (int j = 0; j < 8; j++) { d1[j] = 0.f; d2[j] = 0.f; }
#pragma unroll
  for (int dy = 0; dy < 3; dy++) {
    int zr = r + dy;                        // zb row = image row y0+r-1+dy
    {
      const _Float16* z = &zb[0][zr * ZSTR];
      f16x8 cv = *reinterpret_cast<const f16x8*>(&z[seg * 8]);
      float lv = (seg == 0) ? 0.f : (float)z[seg * 8 - 1];
      float rv = (seg == 31) ? 0.f : (float)z[seg * 8 + 8];
#pragma unroll
      for (int j = 0; j < 8; j++) {
        float xl = (j == 0) ? lv : (float)cv[j - 1];
        float xr = (j == 7) ? rv : (float)cv[j + 1];
        d1[j] += xl * w1[dy * 3] + (float)cv[j] * w1[dy * 3 + 1] + xr * w1[dy * 3 + 2];
      }
    }
    {
      const _Float16* z = &zb[1][zr * ZSTR];
      f16x8 cv = *reinterpret_cast<const f16x8*>(&z[seg * 8]);
      float lv = (seg == 0) ? 0.f : (float)z[seg * 8 - 1];
      float rv = (seg == 31) ? 0.f : (float)z[seg * 8 + 8];
#pragma unroll
      for (int j = 0; j < 8; j++) {
        float xl = (j == 0) ? lv : (float)cv[j - 1];
        float xr = (j == 7) ? rv : (float)cv[j + 1];
        d2[j] += xl * w2[dy * 3] + (float)cv[j] * w2[dy * 3 + 1] + xr * w2[dy * 3 + 2];
      }
    }
  }
  float o[8];
#pragma unroll
  for (int j = 0; j < 8; j++)
    o[j] = 0.5f * d1[j] * (1.f + erff(d1[j] * 0.70710678118654752f)) * d2[j];
  unsigned short* gp = (cg < 96)
      ? g1 + ((size_t)(b * 96 + cg)) * HWC
      : g2 + ((size_t)(b * 48 + (cg - 96))) * HWC;
  store8bf(gp + (y0 + r) * 256 + seg * 8, o);
}

// ---------------------------------------------------------------------------
extern "C" void kernel_launch(void* const* d_in, const int* in_sizes, int n_in,
                              void* d_out, int out_size, void* d_ws,
                              size_t ws_size, hipStream_t stream) {
  (void)in_sizes; (void)n_in; (void)out_size; (void)ws_size;
  const float* x   = (const float*)d_in[0];
  const float* n1w = (const float*)d_in[1];
  const float* n1b = (const float*)d_in[2];
  const float* awh = (const float*)d_in[3];   // [288,48]
  const float* adw = (const float*)d_in[4];   // [288,1,3,3]
  const float* anw = (const float*)d_in[5];   // [96]
  const float* anb = (const float*)d_in[6];
  const float* awo = (const float*)d_in[7];   // [48,96]
  const float* n2w = (const float*)d_in[8];
  const float* n2b = (const float*)d_in[9];
  const float* fwi = (const float*)d_in[10];  // [288,48]
  const float* fff = (const float*)d_in[11];  // [288,1,1,8,5]
  const float* fdw = (const float*)d_in[12];  // [288,1,3,3]
  const float* fwo = (const float*)d_in[13];  // [48,144]

  unsigned short* QKV  = (unsigned short*)d_ws;                       // 75.5 MB
  unsigned short* HID  = (unsigned short*)((char*)d_ws + 75497472);   // 75.5 MB
  unsigned short* U    = (unsigned short*)((char*)d_ws + 150994944);  // 25.2 MB
  unsigned short* X1   = (unsigned short*)((char*)d_ws + 176160768);  // 12.6 MB
  unsigned short* G2   = (unsigned short*)((char*)d_ws + 188743680);  // 12.6 MB
  unsigned short* WP   = (unsigned short*)((char*)d_ws + 201326592);  // 96 KB
  unsigned short* CMAT = (unsigned short*)((char*)d_ws + 201424896);  // 2.36 MB
  unsigned short* WA = WP;             // awh padded [288][64]
  unsigned short* WO = WP + 18432;     // awo [48][96]
  unsigned short* WI = WP + 23040;     // fwi padded [288][64]
  unsigned short* WF = WP + 41472;     // fwo padded [48][160]

  k_prep_w<<<960, 64, 0, stream>>>(awh, awo, fwi, fwo, fff, WP, CMAT);
  // FSAS: hidden = W_h * LN1(x)  [LN fused]
  k_gemm<288, 48, 64, 1, 0><<<2048, 256, 0, stream>>>(WA, x, nullptr, n1w,
                                                      n1b, nullptr, HID);
  // q,k fused patch conv -> U ; v dwconv -> QKV (merged kernel)
  k_fsas_fused<<<2 * 192 * 32, 256, 0, stream>>>(HID, adw, U, QKV);
  // x1 = x + W_o*(LN(u)*v); y = W_in*LN(x1)  [merged, x1 tile in LDS]
  k_gemm23<<<2048, 256, 0, stream>>>(WO, WI, U, QKV, anw, anb, n2w, n2b, x,
                                     X1);
  // spectral filter (MFMA circulant, z in LDS) + dwconv + GELU gate
  k_dffn_mfma<<<2 * 144 * 32, 256, 0, stream>>>(QKV, CMAT, fdw, U, G2);
  // out = x1 + W_out * g  (g split U/G2), fp32 output
  k_gemm<48, 144, 160, 0, 2><<<2048, 256, 0, stream>>>(WF, U, G2, nullptr,
                                                       nullptr, X1,
                                                       (float*)d_out);
}

// Round 14
// 271.942 us; speedup vs baseline: 1.0193x; 1.0042x over previous
//
#include <hip/hip_runtime.h>
#include <hip/hip_bf16.h>
#include <cstddef>

// FFTformer block. FFTs reduced to 8x8 circular convolutions; conv1x1 GEMMs
// on MFMA (bf16 in, fp32 acc), LN/gate fused into GEMM staging, weights
// pre-converted to padded bf16. FSAS dwconv(q,k)+patch conv via per-row real
// DFT-8; v-dwconv absorbed into the same kernel (NO swizzle: heterogeneous
// blocks rely on round-robin interleave; r7 measured -14us when segregated).
// DFFN: spectral filter as per-channel 64x64 circulant on MFMA with z in
// LDS, fused dwconv3 + erff GELU gate (r12: rational erf regressed);
// XCD-bijective swizzle (r8: FETCH 127->39MB).  r9: gemm2+gemm3 merged.
// r13: epilogue ping-pong (neutral, kept).  r14: T14 async-stage in dffn —
// h=1's As/Bs3 global loads issued under h=0's MFMA (reg-staged, write-late);
// barriers 5->4.
// B=2, d=48, H=W=256, P=8.  Workspace (ws_size = 256 MiB):
//   [0,           75,497,472)  QKV bf16 [2,288,HW]  (v; later y)
//   [75,497,472, 150,994,944)  HID bf16 [2,288,HW]
//   [150,994,944,176,160,768)  U   bf16 [2,96,HW]   (out96/u -> g1)
//   [176,160,768,188,743,680)  X1  bf16 [2,48,HW]
//   [188,743,680,201,326,592)  G2  bf16 [2,48,HW]
//   [201,326,592,201,424,896)  WPAD bf16 (awh64 | awo96 | fwi64 | fwo160)
//   [201,424,896,203,784,192)  CMAT bf16 [288][64][64] circulants

constexpr int HWC = 65536;   // 256*256

typedef short short8 __attribute__((ext_vector_type(8)));
typedef __bf16 bf16x8 __attribute__((ext_vector_type(8)));
typedef float f32x4 __attribute__((ext_vector_type(4)));
typedef _Float16 f16x8 __attribute__((ext_vector_type(8)));
typedef _Float16 f16x4 __attribute__((ext_vector_type(4)));

__device__ inline unsigned short f2bf(float f) {
  __hip_bfloat16 h = __float2bfloat16(f);
  return *reinterpret_cast<unsigned short*>(&h);
}
__device__ inline float bf2f(unsigned short u) {
  __hip_bfloat16 h;
  *reinterpret_cast<unsigned short*>(&h) = u;
  return __bfloat162float(h);
}

union V8 { uint4 v; unsigned short us[8]; short s[8]; };

__device__ inline void load8f(const unsigned short* p, float* f) {
  V8 u; u.v = *reinterpret_cast<const uint4*>(p);
#pragma unroll
  for (int j = 0; j < 8; j++) f[j] = bf2f(u.us[j]);
}
__device__ inline void store8bf(unsigned short* p, const float* f) {
  V8 u;
#pragma unroll
  for (int j = 0; j < 8; j++) u.us[j] = f2bf(f[j]);
  *reinterpret_cast<uint4*>(p) = u.v;
}

// Real DFT-8 of x[8] -> e = [X0, X1r, X1i, X2r, X2i, X3r, X3i, X4].
__device__ inline void fdft8(const float* x, float* e) {
  const float c = 0.70710678118654752f;
  float t0 = x[0] + x[4], t1 = x[0] - x[4];
  float t2 = x[2] + x[6], t3 = x[2] - x[6];
  float t4 = x[1] + x[5], t5 = x[1] - x[5];
  float t6 = x[3] + x[7], t7 = x[3] - x[7];
  float A = c * (t5 - t7), B = c * (t5 + t7);
  float s1 = t0 + t2, s2 = t4 + t6;
  e[0] = s1 + s2;
  e[7] = s1 - s2;
  e[1] = t1 + A;
  e[5] = t1 - A;
  e[2] = -(B + t3);
  e[6] = t3 - B;
  e[3] = t0 - t2;
  e[4] = t6 - t4;
}

// Inverse DFT-8 of spectrum Z (same bin layout) -> 8 spatial values.
__device__ inline void idft8(const float* Z, float* acc) {
  const float c2 = 0.70710678118654752f;
  float Z0 = Z[0], Z1r = Z[1], Z1i = Z[2], Z2r = Z[3];
  float Z2i = Z[4], Z3r = Z[5], Z3i = Z[6], Z4 = Z[7];
  float u0 = Z0 + Z4, u1 = Z0 - Z4;
  float E = 2.f * Z2r, F = 2.f * (Z1r + Z3r), G = 2.f * (Z1i - Z3i);
  float T = 2.f * Z2i;
  float P = 2.f * c2 * (Z1r - Z1i), Qv = 2.f * c2 * (Z1r + Z1i);
  float R = 2.f * c2 * (Z3r + Z3i), S = 2.f * c2 * (Z3r - Z3i);
  acc[0] = 0.125f * (u0 + E + F);
  acc[4] = 0.125f * (u0 + E - F);
  acc[2] = 0.125f * (u0 - E - G);
  acc[6] = 0.125f * (u0 - E + G);
  acc[1] = 0.125f * (u1 + P - T - R);
  acc[3] = 0.125f * (u1 - Qv + T + S);
  acc[5] = 0.125f * (u1 - P - T + R);
  acc[7] = 0.125f * (u1 + Qv + T - S);
}

__device__ const float c_cos8[8] = {
    1.f, 0.70710678118654752f, 0.f, -0.70710678118654752f,
    -1.f, -0.70710678118654752f, 0.f, 0.70710678118654752f};

// ---------------------------------------------------------------------------
// Pre-convert weights fp32 -> bf16 padded (rows 0..671).  Rows 672..959 build
// CMAT: Cmat[c][m][k] (bf16) 64x64 circulant of s_c = irfft2(ffn_fft[c]).
__global__ __launch_bounds__(64) void k_prep_w(
    const float* __restrict__ awh, const float* __restrict__ awo,
    const float* __restrict__ fwi, const float* __restrict__ fwo,
    const float* __restrict__ fftw, unsigned short* __restrict__ wp,
    unsigned short* __restrict__ cmat) {
  __shared__ float sf[64];
  int row = blockIdx.x, t = threadIdx.x;
  if (row >= 672) {
    int c = row - 672;
    int a = t >> 3, b2 = t & 7;
    const float* W = fftw + c * 40;  // [8][5]
    float acc = 0.f;
    for (int u = 0; u < 8; u++) {
      for (int v = 0; v < 8; v++) {
        float wv;
        if (v <= 4) {
          if (v == 0 || v == 4)
            wv = 0.5f * (W[u * 5 + v] + W[((8 - u) & 7) * 5 + v]);
          else
            wv = W[u * 5 + v];
        } else {
          wv = W[((8 - u) & 7) * 5 + (8 - v)];
        }
        acc += wv * c_cos8[(u * a + v * b2) & 7];
      }
    }
    sf[t] = acc * (1.f / 64.f);
    __syncthreads();
    unsigned short* cp = cmat + (size_t)c * 4096 + t * 64;
    for (int k8 = 0; k8 < 64; k8 += 8) {
      float v[8];
      int ka = k8 >> 3;
      int ia = ((a - ka) & 7) * 8;
#pragma unroll
      for (int j = 0; j < 8; j++) v[j] = sf[ia + ((b2 - j) & 7)];
      store8bf(cp + k8, v);
    }
    return;
  }
  const float* src; int K, KP; unsigned short* dst;
  if (row < 288)      { src = awh + row * 48;        K = 48;  KP = 64;
                        dst = wp + row * 64; }
  else if (row < 336) { int r = row - 288; src = awo + r * 96; K = 96; KP = 96;
                        dst = wp + 18432 + r * 96; }
  else if (row < 624) { int r = row - 336; src = fwi + r * 48; K = 48; KP = 64;
                        dst = wp + 23040 + r * 64; }
  else                { int r = row - 624; src = fwo + r * 144; K = 144; KP = 160;
                        dst = wp + 41472 + r * 160; }
  for (int k = t; k < KP; k += 64) dst[k] = f2bf(k < K ? src[k] : 0.f);
}

// ---------------------------------------------------------------------------
// MFMA GEMM: out[M x N] = Wb[M x KP(bf16)] * X[K x N], 64 px/block.
// XF: 0 none (K split 96/48 s1/s2), 1 LN48 fp32 s1.
// EPI: 0 write bf16[M]; 2 += bf16 res -> fp32.
// r13: Es ping-pong (Xs / Es2) -> one barrier per t instead of two.
template <int M, int K, int KP, int XF, int EPI>
__global__ __launch_bounds__(256) void k_gemm(
    const unsigned short* __restrict__ wb, const void* __restrict__ s1,
    const unsigned short* __restrict__ s2, const float* __restrict__ lnw,
    const float* __restrict__ lnb, const void* __restrict__ res,
    void* __restrict__ out) {
  constexpr int STRIDE = KP + 8;
  constexpr int KS = KP / 32;
  constexpr int NT = (M + 63) / 64;
  __shared__ __align__(16) short Xs[64 * STRIDE];   // staging, then epilogue A
  __shared__ __align__(16) short Es2[(NT > 1) ? 64 * 72 : 4];  // epilogue B
  __shared__ float redS[4][64], redS2[4][64], mus[64], invs[64];

  int tid = threadIdx.x;
  unsigned bid = blockIdx.x;
  int b = (int)(bid >> 10);
  int hw0 = (int)(bid & 1023) * 64;

  // stage X transposed: Xs[col][k]
  if (XF == 1) {
    const float* xp = (const float*)s1 + (size_t)b * 48 * HWC + hw0;
    for (int idx = tid; idx < 48 * 16; idx += 256) {
      int c = idx >> 4, colg = (idx & 15) * 4;
      float4 f = *reinterpret_cast<const float4*>(xp + (size_t)c * HWC + colg);
      Xs[(colg + 0) * STRIDE + c] = (short)f2bf(f.x);
      Xs[(colg + 1) * STRIDE + c] = (short)f2bf(f.y);
      Xs[(colg + 2) * STRIDE + c] = (short)f2bf(f.z);
      Xs[(colg + 3) * STRIDE + c] = (short)f2bf(f.w);
    }
  } else {
    const unsigned short* p1 =
        (const unsigned short*)s1 + (size_t)b * 96 * HWC + hw0;
    const unsigned short* p2 = s2 + (size_t)b * 48 * HWC + hw0;
    for (int idx = tid; idx < K * 16; idx += 256) {
      int c = idx >> 4, colg = (idx & 15) * 4;
      const unsigned short* p =
          (c < 96) ? (p1 + (size_t)c * HWC + colg)
                   : (p2 + (size_t)(c - 96) * HWC + colg);
      ushort4 uv = *reinterpret_cast<const ushort4*>(p);
      Xs[(colg + 0) * STRIDE + c] = (short)uv.x;
      Xs[(colg + 1) * STRIDE + c] = (short)uv.y;
      Xs[(colg + 2) * STRIDE + c] = (short)uv.z;
      Xs[(colg + 3) * STRIDE + c] = (short)uv.w;
    }
  }

  if constexpr (KP > K) {
    constexpr int PAD = KP - K;
    for (int idx = tid; idx < 64 * PAD; idx += 256) {
      int col = idx / PAD, c = K + (idx % PAD);
      Xs[col * STRIDE + c] = 0;
    }
  }

  if (XF == 1) {
    constexpr int KC = 48;
    __syncthreads();
    {
      int col = tid & 63, q = tid >> 6;
      float s = 0.f, s2 = 0.f;
      for (int c = q * (KC / 4); c < (q + 1) * (KC / 4); c++) {
        float v = bf2f((unsigned short)Xs[col * STRIDE + c]);
        s += v; s2 += v * v;
      }
      redS[q][col] = s; redS2[q][col] = s2;
    }
    __syncthreads();
    if (tid < 64) {
      float ss = redS[0][tid] + redS[1][tid] + redS[2][tid] + redS[3][tid];
      float ss2 = redS2[0][tid] + redS2[1][tid] + redS2[2][tid] + redS2[3][tid];
      float mu = ss * (1.f / KC);
      float var = ss2 * (1.f / KC) - mu * mu;
      mus[tid] = mu; invs[tid] = rsqrtf(var + 1e-5f);
    }
    __syncthreads();
    for (int idx = tid; idx < KC * 64; idx += 256) {
      int c = idx >> 6, col = idx & 63;
      float v = bf2f((unsigned short)Xs[col * STRIDE + c]);
      v = (v - mus[col]) * invs[col] * lnw[c] + lnb[c];
      Xs[col * STRIDE + c] = (short)f2bf(v);
    }
  }
  __syncthreads();

  int lane = tid & 63, wvi = tid >> 6;
  int quad = lane >> 4, mc = lane & 15;
  int kbase = quad * 8;

  short8 bfr[4][KS];
#pragma unroll
  for (int ns = 0; ns < 4; ns++)
#pragma unroll
    for (int ks = 0; ks < KS; ks++)
      bfr[ns][ks] = *reinterpret_cast<const short8*>(
          Xs + (ns * 16 + mc) * STRIDE + ks * 32 + kbase);

  __syncthreads();   // all bfr loads done; Xs reusable as epilogue buffer
#pragma unroll
  for (int t = 0; t < NT; t++) {
    int mb = (wvi + 4 * t) * 16;
    f32x4 accs[4];
    if (mb < M) {
      short8 afr[KS];
#pragma unroll
      for (int ks = 0; ks < KS; ks++)
        afr[ks] = *reinterpret_cast<const short8*>(
            wb + (size_t)(mb + mc) * KP + ks * 32 + kbase);
#pragma unroll
      for (int ns = 0; ns < 4; ns++) {
        f32x4 acc = {0.f, 0.f, 0.f, 0.f};
#pragma unroll
        for (int ks = 0; ks < KS; ks++)
          acc = __builtin_amdgcn_mfma_f32_16x16x32_bf16(
              __builtin_bit_cast(bf16x8, afr[ks]),
              __builtin_bit_cast(bf16x8, bfr[ns][ks]), acc, 0, 0, 0);
        accs[ns] = acc;
      }
    }
    short* Est = (NT > 1 && (t & 1)) ? Es2 : Xs;   // ping-pong
    if (mb < M) {
      int chl = wvi * 16 + quad * 4;
#pragma unroll
      for (int ns = 0; ns < 4; ns++)
#pragma unroll
        for (int r = 0; r < 4; r++)
          Est[(chl + r) * 72 + ns * 16 + mc] = (short)f2bf(accs[ns][r]);
    }
    __syncthreads();
#pragma unroll
    for (int i = 0; i < 2; i++) {
      int chl = (tid >> 3) + 32 * i;
      int px0 = (tid & 7) * 8;
      int m = 64 * t + chl;
      if (m < M) {
        V8 ev;
        ev.v = *reinterpret_cast<const uint4*>(Est + chl * 72 + px0);
        size_t off = ((size_t)(b * ((EPI == 0) ? M : 48) + m)) * HWC + hw0 + px0;
        if (EPI == 0) {
          *reinterpret_cast<uint4*>((unsigned short*)out + off) = ev.v;
        } else {
          V8 rv;
          rv.v = *reinterpret_cast<const uint4*>((const unsigned short*)res + off);
          float* op = (float*)out + off;
          float4 oa, ob;
          oa.x = bf2f(rv.us[0]) + bf2f(ev.us[0]);
          oa.y = bf2f(rv.us[1]) + bf2f(ev.us[1]);
          oa.z = bf2f(rv.us[2]) + bf2f(ev.us[2]);
          oa.w = bf2f(rv.us[3]) + bf2f(ev.us[3]);
          ob.x = bf2f(rv.us[4]) + bf2f(ev.us[4]);
          ob.y = bf2f(rv.us[5]) + bf2f(ev.us[5]);
          ob.z = bf2f(rv.us[6]) + bf2f(ev.us[6]);
          ob.w = bf2f(rv.us[7]) + bf2f(ev.us[7]);
          *reinterpret_cast<float4*>(op) = oa;
          *reinterpret_cast<float4*>(op + 4) = ob;
        }
      }
    }
  }
}

// ---------------------------------------------------------------------------
// Merged gemm2+gemm3 (r9 proven): per 64-px tile,
//   x1 = x + W_o * (LN96(u) * v)        [write X1 bf16; keep tile in LDS]
//   y  = W_in * LN48(x1)                [write QKV ch 0..287]
// r13: MFMA2 epilogue ping-pongs Xs/Vs (Vs free once bfr2 is in registers).
__global__ __launch_bounds__(256) void k_gemm23(
    const unsigned short* __restrict__ wo, const unsigned short* __restrict__ wi,
    const unsigned short* __restrict__ u, unsigned short* __restrict__ qkv,
    const float* __restrict__ anw, const float* __restrict__ anb,
    const float* __restrict__ n2w, const float* __restrict__ n2b,
    const float* __restrict__ x, unsigned short* __restrict__ x1) {
  constexpr int S1 = 104;  // stage1 stride (96+8)
  constexpr int S2 = 72;   // stage2 stride (64+8)
  __shared__ __align__(16) short Xs[64 * S1];   // stage1 u; then epilogue A
  __shared__ __align__(16) short Vs[64 * S1];   // stage1 v; x1; epilogue B
  __shared__ float redS[4][64], redS2[4][64], mus[64], invs[64];

  int tid = threadIdx.x;
  unsigned bid = blockIdx.x;
  int b = (int)(bid >> 10);
  int hw0 = (int)(bid & 1023) * 64;

  // ---- stage1: u + v transposed
  {
    const unsigned short* up = u + (size_t)b * 96 * HWC + hw0;
    const unsigned short* vp = qkv + ((size_t)(b * 288 + 192)) * HWC + hw0;
    for (int idx = tid; idx < 96 * 16; idx += 256) {
      int c = idx >> 4, colg = (idx & 15) * 4;
      ushort4 uv = *reinterpret_cast<const ushort4*>(up + (size_t)c * HWC + colg);
      Xs[(colg + 0) * S1 + c] = (short)uv.x;
      Xs[(colg + 1) * S1 + c] = (short)uv.y;
      Xs[(colg + 2) * S1 + c] = (short)uv.z;
      Xs[(colg + 3) * S1 + c] = (short)uv.w;
      ushort4 vv = *reinterpret_cast<const ushort4*>(vp + (size_t)c * HWC + colg);
      Vs[(colg + 0) * S1 + c] = (short)vv.x;
      Vs[(colg + 1) * S1 + c] = (short)vv.y;
      Vs[(colg + 2) * S1 + c] = (short)vv.z;
      Vs[(colg + 3) * S1 + c] = (short)vv.w;
    }
  }
  // ---- LN96 + v-gate
  __syncthreads();
  {
    int col = tid & 63, q = tid >> 6;
    float s = 0.f, s2 = 0.f;
    for (int c = q * 24; c < (q + 1) * 24; c++) {
      float v = bf2f((unsigned short)Xs[col * S1 + c]);
      s += v; s2 += v * v;
    }
    redS[q][col] = s; redS2[q][col] = s2;
  }
  __syncthreads();
  if (tid < 64) {
    float ss = redS[0][tid] + redS[1][tid] + redS[2][tid] + redS[3][tid];
    float ss2 = redS2[0][tid] + redS2[1][tid] + redS2[2][tid] + redS2[3][tid];
    float mu = ss * (1.f / 96.f);
    float var = ss2 * (1.f / 96.f) - mu * mu;
    mus[tid] = mu; invs[tid] = rsqrtf(var + 1e-5f);
  }
  __syncthreads();
  for (int idx = tid; idx < 96 * 64; idx += 256) {
    int c = idx >> 6, col = idx & 63;
    float v = bf2f((unsigned short)Xs[col * S1 + c]);
    v = (v - mus[col]) * invs[col] * anw[c] + anb[c];
    v *= bf2f((unsigned short)Vs[col * S1 + c]);
    Xs[col * S1 + c] = (short)f2bf(v);
  }
  __syncthreads();

  int lane = tid & 63, wvi = tid >> 6;
  int quad = lane >> 4, mc = lane & 15;
  int kbase = quad * 8;

  // ---- MFMA1: W_o[48x96] (waves 0..2 active)
  short8 bfr1[4][3];
#pragma unroll
  for (int ns = 0; ns < 4; ns++)
#pragma unroll
    for (int ks = 0; ks < 3; ks++)
      bfr1[ns][ks] = *reinterpret_cast<const short8*>(
          Xs + (ns * 16 + mc) * S1 + ks * 32 + kbase);
  bool act1 = (wvi < 3);
  f32x4 acc1[4];
  if (act1) {
    int mb = wvi * 16;
    short8 afr[3];
#pragma unroll
    for (int ks = 0; ks < 3; ks++)
      afr[ks] = *reinterpret_cast<const short8*>(
          wo + (size_t)(mb + mc) * 96 + ks * 32 + kbase);
#pragma unroll
    for (int ns = 0; ns < 4; ns++) {
      f32x4 acc = {0.f, 0.f, 0.f, 0.f};
#pragma unroll
      for (int ks = 0; ks < 3; ks++)
        acc = __builtin_amdgcn_mfma_f32_16x16x32_bf16(
            __builtin_bit_cast(bf16x8, afr[ks]),
            __builtin_bit_cast(bf16x8, bfr1[ns][ks]), acc, 0, 0, 0);
      acc1[ns] = acc;
    }
  }
  __syncthreads();   // everyone done reading Xs/Vs stage1 data
  // ---- x1 tile (acc + residual) into Vs as [px][ch], stride S2
  if (act1) {
    int chl = wvi * 16 + quad * 4;
#pragma unroll
    for (int ns = 0; ns < 4; ns++) {
      int px = ns * 16 + mc;
#pragma unroll
      for (int r = 0; r < 4; r++) {
        int m = chl + r;
        float xr = x[((size_t)(b * 48 + m)) * HWC + hw0 + px];
        Vs[px * S2 + m] = (short)f2bf(acc1[ns][r] + xr);
      }
    }
  }
  // zero-pad ch 48..63 (KP2=64)
  for (int idx = tid; idx < 64 * 16; idx += 256) {
    int col = idx >> 4, c = 48 + (idx & 15);
    Vs[col * S2 + c] = 0;
  }
  __syncthreads();
  // ---- coop X1 HBM write (bf16 [ch][px]) + LN48 stats (both read-only)
  for (int u2 = tid; u2 < 48 * 8; u2 += 256) {
    int m = u2 >> 3, px0 = (u2 & 7) * 8;
    V8 pk;
#pragma unroll
    for (int j = 0; j < 8; j++)
      pk.us[j] = (unsigned short)Vs[(px0 + j) * S2 + m];
    *reinterpret_cast<uint4*>(x1 + ((size_t)(b * 48 + m)) * HWC + hw0 + px0) =
        pk.v;
  }
  {
    int col = tid & 63, q = tid >> 6;
    float s = 0.f, s2 = 0.f;
    for (int c = q * 12; c < (q + 1) * 12; c++) {
      float v = bf2f((unsigned short)Vs[col * S2 + c]);
      s += v; s2 += v * v;
    }
    redS[q][col] = s; redS2[q][col] = s2;
  }
  __syncthreads();
  if (tid < 64) {
    float ss = redS[0][tid] + redS[1][tid] + redS[2][tid] + redS[3][tid];
    float ss2 = redS2[0][tid] + redS2[1][tid] + redS2[2][tid] + redS2[3][tid];
    float mu = ss * (1.f / 48.f);
    float var = ss2 * (1.f / 48.f) - mu * mu;
    mus[tid] = mu; invs[tid] = rsqrtf(var + 1e-5f);
  }
  __syncthreads();
  for (int idx = tid; idx < 48 * 64; idx += 256) {
    int c = idx >> 6, col = idx & 63;
    float v = bf2f((unsigned short)Vs[col * S2 + c]);
    v = (v - mus[col]) * invs[col] * n2w[c] + n2b[c];
    Vs[col * S2 + c] = (short)f2bf(v);
  }
  __syncthreads();

  // ---- MFMA2: W_in[288x64(pad)] x LN48(x1) -> y (QKV ch 0..287)
  short8 bfr2[4][2];
#pragma unroll
  for (int ns = 0; ns < 4; ns++)
#pragma unroll
    for (int ks = 0; ks < 2; ks++)
      bfr2[ns][ks] = *reinterpret_cast<const short8*>(
          Vs + (ns * 16 + mc) * S2 + ks * 32 + kbase);
  __syncthreads();   // all bfr2 loads done; Xs/Vs reusable as epilogue buffers
#pragma unroll
  for (int t = 0; t < 5; t++) {
    int mb = (wvi + 4 * t) * 16;
    f32x4 accs[4];
    if (mb < 288) {
      short8 afr[2];
#pragma unroll
      for (int ks = 0; ks < 2; ks++)
        afr[ks] = *reinterpret_cast<const short8*>(
            wi + (size_t)(mb + mc) * 64 + ks * 32 + kbase);
#pragma unroll
      for (int ns = 0; ns < 4; ns++) {
        f32x4 acc = {0.f, 0.f, 0.f, 0.f};
#pragma unroll
        for (int ks = 0; ks < 2; ks++)
          acc = __builtin_amdgcn_mfma_f32_16x16x32_bf16(
              __builtin_bit_cast(bf16x8, afr[ks]),
              __builtin_bit_cast(bf16x8, bfr2[ns][ks]), acc, 0, 0, 0);
        accs[ns] = acc;
      }
    }
    short* Est = (t & 1) ? Vs : Xs;   // ping-pong
    if (mb < 288) {
      int chl = wvi * 16 + quad * 4;
#pragma unroll
      for (int ns = 0; ns < 4; ns++)
#pragma unroll
        for (int r = 0; r < 4; r++)
          Est[(chl + r) * 72 + ns * 16 + mc] = (short)f2bf(accs[ns][r]);
    }
    __syncthreads();
#pragma unroll
    for (int i = 0; i < 2; i++) {
      int chl = (tid >> 3) + 32 * i;
      int px0 = (tid & 7) * 8;
      int m = 64 * t + chl;
      if (m < 288) {
        V8 ev;
        ev.v = *reinterpret_cast<const uint4*>(Est + chl * 72 + px0);
        *reinterpret_cast<uint4*>(
            qkv + ((size_t)(b * 288 + m)) * HWC + hw0 + px0) = ev.v;
      }
    }
  }
}

// ---------------------------------------------------------------------------
// FSAS fused + v-dwconv.  cc<96: dwconv3(q,k) on the fly, per-row DFT-8,
// freq-domain circular conv, idft8.  cc>=96: v dwconv3.  NO blockIdx swizzle.
__global__ __launch_bounds__(256) void k_fsas_fused(
    const unsigned short* __restrict__ hid, const float* __restrict__ dw,
    unsigned short* __restrict__ out, unsigned short* __restrict__ qkv) {
  constexpr int LSTR = 260;            // f32/row: 256 + 4 pad
  __shared__ __align__(16) float qs[8 * LSTR];
  __shared__ __align__(16) float kt[8 * LSTR];
  int tid = threadIdx.x;
  unsigned bid = blockIdx.x;                 // b*192*32 + cc*32 + py
  int py = (int)(bid & 31);
  unsigned t = bid >> 5;
  int cc = (int)(t % 192u);
  int b = (int)(t / 192u);
  int r = tid >> 5, seg = tid & 31, lane = tid & 63;

  if (cc >= 96) {
    int c = 96 + cc;                         // 192..287
    const unsigned short* ip = hid + ((size_t)(b * 288 + c)) * HWC;
    float wv[9];
#pragma unroll
    for (int k = 0; k < 9; k++) wv[k] = dw[c * 9 + k];
    int y = py * 8 + r;
    float f[3][8];
#pragma unroll
    for (int dy = 0; dy < 3; dy++) {
      int yy = y + dy - 1;
      if (yy >= 0 && yy < 256) {
        load8f(ip + yy * 256 + seg * 8, f[dy]);
      } else {
#pragma unroll
        for (int j = 0; j < 8; j++) f[dy][j] = 0.f;
      }
    }
    float o[8];
#pragma unroll
    for (int dy = 0; dy < 3; dy++) {
      float lv = __shfl(f[dy][7], lane - 1, 64);
      float rv = __shfl(f[dy][0], lane + 1, 64);
      if (seg == 0) lv = 0.f;
      if (seg == 31) rv = 0.f;
#pragma unroll
      for (int j = 0; j < 8; j++) {
        float xl = (j == 0) ? lv : f[dy][j - 1];
        float xr = (j == 7) ? rv : f[dy][j + 1];
        float v = xl * wv[dy * 3] + f[dy][j] * wv[dy * 3 + 1] + xr * wv[dy * 3 + 2];
        o[j] = (dy == 0) ? v : o[j] + v;
      }
    }
    store8bf(qkv + ((size_t)(b * 288 + c)) * HWC + y * 256 + seg * 8, o);
    return;
  }

  int c = cc;
  const unsigned short* qp = hid + ((size_t)(b * 288 + c)) * HWC;
  const unsigned short* kp = hid + ((size_t)(b * 288 + 96 + c)) * HWC;
  float w1[9], w2[9];
#pragma unroll
  for (int k = 0; k < 9; k++) {
    w1[k] = dw[c * 9 + k];
    w2[k] = dw[(96 + c) * 9 + k];
  }
  int y = py * 8 + r;
  float f1[3][8], f2[3][8];
#pragma unroll
  for (int dy = 0; dy < 3; dy++) {
    int yy = y + dy - 1;
    if (yy >= 0 && yy < 256) {
      load8f(qp + yy * 256 + seg * 8, f1[dy]);
      load8f(kp + yy * 256 + seg * 8, f2[dy]);
    } else {
#pragma unroll
      for (int j = 0; j < 8; j++) { f1[dy][j] = 0.f; f2[dy][j] = 0.f; }
    }
  }
  float d1[8], d2[8];
#pragma unroll
  for (int j = 0; j < 8; j++) { d1[j] = 0.f; d2[j] = 0.f; }
#pragma unroll
  for (int dy = 0; dy < 3; dy++) {
    float lv1 = __shfl(f1[dy][7], lane - 1, 64);
    float rv1 = __shfl(f1[dy][0], lane + 1, 64);
    float lv2 = __shfl(f2[dy][7], lane - 1, 64);
    float rv2 = __shfl(f2[dy][0], lane + 1, 64);
    if (seg == 0) { lv1 = 0.f; lv2 = 0.f; }
    if (seg == 31) { rv1 = 0.f; rv2 = 0.f; }
#pragma unroll
    for (int j = 0; j < 8; j++) {
      float xl1 = (j == 0) ? lv1 : f1[dy][j - 1];
      float xr1 = (j == 7) ? rv1 : f1[dy][j + 1];
      float xl2 = (j == 0) ? lv2 : f2[dy][j - 1];
      float xr2 = (j == 7) ? rv2 : f2[dy][j + 1];
      d1[j] += xl1 * w1[dy * 3] + f1[dy][j] * w1[dy * 3 + 1] + xr1 * w1[dy * 3 + 2];
      d2[j] += xl2 * w2[dy * 3] + f2[dy][j] * w2[dy * 3 + 1] + xr2 * w2[dy * 3 + 2];
    }
  }
  {
    float e1[8], e2[8];
    fdft8(d1, e1);
    fdft8(d2, e2);
    float4 a1 = {e1[0], e1[1], e1[2], e1[3]};
    float4 b1 = {e1[4], e1[5], e1[6], e1[7]};
    float4 a2 = {e2[0], e2[1], e2[2], e2[3]};
    float4 b2 = {e2[4], e2[5], e2[6], e2[7]};
    *reinterpret_cast<float4*>(&qs[r * LSTR + seg * 8]) = a1;
    *reinterpret_cast<float4*>(&qs[r * LSTR + seg * 8 + 4]) = b1;
    *reinterpret_cast<float4*>(&kt[r * LSTR + seg * 8]) = a2;
    *reinterpret_cast<float4*>(&kt[r * LSTR + seg * 8 + 4]) = b2;
  }
  __syncthreads();
  int p = tid >> 3, a = tid & 7;
  float Z[8];
#pragma unroll
  for (int j = 0; j < 8; j++) Z[j] = 0.f;
#pragma unroll
  for (int i = 0; i < 8; i++) {
    float4 qa = *reinterpret_cast<const float4*>(&qs[i * LSTR + p * 8]);
    float4 qb = *reinterpret_cast<const float4*>(&qs[i * LSTR + p * 8 + 4]);
    int ar = (a - i) & 7;
    float4 ka = *reinterpret_cast<const float4*>(&kt[ar * LSTR + p * 8]);
    float4 kb = *reinterpret_cast<const float4*>(&kt[ar * LSTR + p * 8 + 4]);
    Z[0] += qa.x * ka.x;
    Z[7] += qb.w * kb.w;
    Z[1] += qa.y * ka.y - qa.z * ka.z;
    Z[2] += qa.y * ka.z + qa.z * ka.y;
    Z[3] += qa.w * ka.w - qb.x * kb.x;
    Z[4] += qa.w * kb.x + qb.x * ka.w;
    Z[5] += qb.y * kb.y - qb.z * kb.z;
    Z[6] += qb.y * kb.z + qb.z * kb.y;
  }
  float acc[8];
  idft8(Z, acc);
  store8bf(out + ((size_t)(b * 96 + c)) * HWC + (py * 8 + a) * 256 + p * 8,
           acc);
}

// ---------------------------------------------------------------------------
// DFFN fused on MFMA: per channel pair (cg, cg+144), slab py: z = C_c * y
// per patch via 64x32 circulant MFMA + halo MFMAs, z in LDS, then dwconv3 +
// erff GELU gate.  XCD-bijective swizzle (r8).  r14: T14 async-stage —
// h-tile As/Bs3 loaded global->regs EARLY (h=1's loads issued under h=0's
// MFMA), written to LDS late; barriers 5->4.
__global__ __launch_bounds__(256) void k_dffn_mfma(
    const unsigned short* __restrict__ y, const unsigned short* __restrict__ cmat,
    const float* __restrict__ dwf, unsigned short* __restrict__ g1,
    unsigned short* __restrict__ g2) {
  constexpr int ZSTR = 264;
  __shared__ __align__(16) short As[64 * 72];
  __shared__ __align__(16) short Bs3[3][32 * 72];
  __shared__ __align__(16) _Float16 zb[2][10 * ZSTR];
  int tid = threadIdx.x;
  unsigned hw = blockIdx.x;                  // nwg = 2*144*32 = 9216
  unsigned bid = (hw & 7u) * 1152u + (hw >> 3);
  int py = (int)(bid & 31);
  int cg = (int)((bid >> 5) % 144u);
  int b  = (int)((bid >> 5) / 144u);
  int y0 = py * 8;
  int lane = tid & 63, wvi = tid >> 6;
  int quad = lane >> 4, mc = lane & 15;
  int kbase = quad * 8;

  // staging coordinates (fixed per thread)
  int am = tid >> 2, akq = (tid & 3) * 16;   // As: 2 x uint4
  int rr = tid >> 5, seg = tid & 31;         // Bs3: 3 x uint4

  // ---- prefetch h=0 into registers
  uint4 rA0, rA1, rB[3];
  {
    const unsigned short* cp = cmat + (size_t)cg * 4096;
    rA0 = *reinterpret_cast<const uint4*>(cp + am * 64 + akq);
    rA1 = *reinterpret_cast<const uint4*>(cp + am * 64 + akq + 8);
    const unsigned short* yp = y + ((size_t)(b * 288 + cg)) * HWC;
#pragma unroll
    for (int s = 0; s < 3; s++) {
      int slab = py - 1 + s;
      uint4 v = {0u, 0u, 0u, 0u};
      if (slab >= 0 && slab < 32)
        v = *reinterpret_cast<const uint4*>(yp + slab * 2048 + rr * 256 +
                                            seg * 8);
      rB[s] = v;
    }
  }

#pragma unroll
  for (int h = 0; h < 2; h++) {
    // write LDS from regs (h=0: first touch; h=1: after h0-end barrier)
    *reinterpret_cast<uint4*>(As + am * 72 + akq) = rA0;
    *reinterpret_cast<uint4*>(As + am * 72 + akq + 8) = rA1;
#pragma unroll
    for (int s = 0; s < 3; s++)
      *reinterpret_cast<uint4*>(&Bs3[s][seg * 72 + rr * 8]) = rB[s];
    __syncthreads();
    // issue h=1 global loads NOW — latency hides under this h's MFMA
    if (h == 0) {
      int c1 = cg + 144;
      const unsigned short* cp = cmat + (size_t)c1 * 4096;
      rA0 = *reinterpret_cast<const uint4*>(cp + am * 64 + akq);
      rA1 = *reinterpret_cast<const uint4*>(cp + am * 64 + akq + 8);
      const unsigned short* yp = y + ((size_t)(b * 288 + c1)) * HWC;
#pragma unroll
      for (int s = 0; s < 3; s++) {
        int slab = py - 1 + s;
        uint4 v = {0u, 0u, 0u, 0u};
        if (slab >= 0 && slab < 32)
          v = *reinterpret_cast<const uint4*>(yp + slab * 2048 + rr * 256 +
                                              seg * 8);
        rB[s] = v;
      }
    }
    // center slab: 64x32, 4 waves x 2 n-halves (proven patchconv core)
    {
      short8 afr[2];
#pragma unroll
      for (int ks = 0; ks < 2; ks++)
        afr[ks] = *reinterpret_cast<const short8*>(
            As + (wvi * 16 + mc) * 72 + ks * 32 + kbase);
#pragma unroll
      for (int nt = 0; nt < 2; nt++) {
        f32x4 acc = {0.f, 0.f, 0.f, 0.f};
#pragma unroll
        for (int ks = 0; ks < 2; ks++) {
          short8 bfr = *reinterpret_cast<const short8*>(
              &Bs3[1][(nt * 16 + mc) * 72 + ks * 32 + kbase]);
          acc = __builtin_amdgcn_mfma_f32_16x16x32_bf16(
              __builtin_bit_cast(bf16x8, afr[ks]),
              __builtin_bit_cast(bf16x8, bfr), acc, 0, 0, 0);
        }
        int p = nt * 16 + mc;
        int m0 = wvi * 16 + quad * 4;
        int a = m0 >> 3, b8 = m0 & 7;
        f16x4 z4;
#pragma unroll
        for (int r = 0; r < 4; r++) z4[r] = (_Float16)acc[r];
        *reinterpret_cast<f16x4*>(&zb[h][(1 + a) * ZSTR + p * 8 + b8]) = z4;
      }
    }
    // halo: wave -> (hb = wvi&1: 0 top/zb0, 1 bottom/zb9; nth = wvi>>1).
    // top: C rows 56..63 x B(py-1) -> z row 7 of those patches = image y0-1.
    // bottom: C rows 0..7 x B(py+1) -> z row 0 = image y0+8.  A rows use
    // (mc&7) duplication so all reads in-bounds; D rows m>=8 discarded.
    {
      int hb = wvi & 1, nth = wvi >> 1;
      int arow = (hb == 0) ? (56 + (mc & 7)) : (mc & 7);
      const short* Bn = &Bs3[(hb == 0) ? 0 : 2][0];
      f32x4 acc = {0.f, 0.f, 0.f, 0.f};
#pragma unroll
      for (int ks = 0; ks < 2; ks++) {
        short8 afr = *reinterpret_cast<const short8*>(
            As + arow * 72 + ks * 32 + kbase);
        short8 bfr = *reinterpret_cast<const short8*>(
            Bn + (nth * 16 + mc) * 72 + ks * 32 + kbase);
        acc = __builtin_amdgcn_mfma_f32_16x16x32_bf16(
            __builtin_bit_cast(bf16x8, afr),
            __builtin_bit_cast(bf16x8, bfr), acc, 0, 0, 0);
      }
      if (quad < 2) {
        int p = nth * 16 + mc;
        int m0 = quad * 4;              // col within patch row (0..7)
        f16x4 z4;
#pragma unroll
        for (int r = 0; r < 4; r++) z4[r] = (_Float16)acc[r];
        *reinterpret_cast<f16x4*>(
            &zb[h][(hb ? 9 : 0) * ZSTR + p * 8 + m0]) = z4;
      }
    }
    __syncthreads();   // h0: all As/Bs3 reads done before h1 overwrite;
                       // h1: zb complete before gate
  }
  // gate phase: dual dwconv3 + exact GELU (erff)
  int r = tid >> 5;
  float w1[9], w2[9];
#pragma unroll
  for (int k = 0; k < 9; k++) {
    w1[k] = dwf[cg * 9 + k];
    w2[k] = dwf[(144 + cg) * 9 + k];
  }
  float d1[8], d2[8];
#pragma unroll
  for (int j = 0; j < 8; j++) { d1[j] = 0.f; d2[j] = 0.f; }
#pragma unroll
  for (int dy = 0; dy < 3; dy++) {
    int zr = r + dy;                        // zb row = image row y0+r-1+dy
    {
      const _Float16* z = &zb[0][zr * ZSTR];
      f16x8 cv = *reinterpret_cast<const f16x8*>(&z[seg * 8]);
      float lv = (seg == 0) ? 0.f : (float)z[seg * 8 - 1];
      float rv = (seg == 31) ? 0.f : (float)z[seg * 8 + 8];
#pragma unroll
      for (int j = 0; j < 8; j++) {
        float xl = (j == 0) ? lv : (float)cv[j - 1];
        float xr = (j == 7) ? rv : (float)cv[j + 1];
        d1[j] += xl * w1[dy * 3] + (float)cv[j] * w1[dy * 3 + 1] + xr * w1[dy * 3 + 2];
      }
    }
    {
      const _Float16* z = &zb[1][zr * ZSTR];
      f16x8 cv = *reinterpret_cast<const f16x8*>(&z[seg * 8]);
      float lv = (seg == 0) ? 0.f : (float)z[seg * 8 - 1];
      float rv = (seg == 31) ? 0.f : (float)z[seg * 8 + 8];
#pragma unroll
      for (int j = 0; j < 8; j++) {
        float xl = (j == 0) ? lv : (float)cv[j - 1];
        float xr = (j == 7) ? rv : (float)cv[j + 1];
        d2[j] += xl * w2[dy * 3] + (float)cv[j] * w2[dy * 3 + 1] + xr * w2[dy * 3 + 2];
      }
    }
  }
  float o[8];
#pragma unroll
  for (int j = 0; j < 8; j++)
    o[j] = 0.5f * d1[j] * (1.f + erff(d1[j] * 0.70710678118654752f)) * d2[j];
  unsigned short* gp = (cg < 96)
      ? g1 + ((size_t)(b * 96 + cg)) * HWC
      : g2 + ((size_t)(b * 48 + (cg - 96))) * HWC;
  store8bf(gp + (y0 + r) * 256 + seg * 8, o);
}

// ---------------------------------------------------------------------------
extern "C" void kernel_launch(void* const* d_in, const int* in_sizes, int n_in,
                              void* d_out, int out_size, void* d_ws,
                              size_t ws_size, hipStream_t stream) {
  (void)in_sizes; (void)n_in; (void)out_size; (void)ws_size;
  const float* x   = (const float*)d_in[0];
  const float* n1w = (const float*)d_in[1];
  const float* n1b = (const float*)d_in[2];
  const float* awh = (const float*)d_in[3];   // [288,48]
  const float* adw = (const float*)d_in[4];   // [288,1,3,3]
  const float* anw = (const float*)d_in[5];   // [96]
  const float* anb = (const float*)d_in[6];
  const float* awo = (const float*)d_in[7];   // [48,96]
  const float* n2w = (const float*)d_in[8];
  const float* n2b = (const float*)d_in[9];
  const float* fwi = (const float*)d_in[10];  // [288,48]
  const float* fff = (const float*)d_in[11];  // [288,1,1,8,5]
  const float* fdw = (const float*)d_in[12];  // [288,1,3,3]
  const float* fwo = (const float*)d_in[13];  // [48,144]

  unsigned short* QKV  = (unsigned short*)d_ws;                       // 75.5 MB
  unsigned short* HID  = (unsigned short*)((char*)d_ws + 75497472);   // 75.5 MB
  unsigned short* U    = (unsigned short*)((char*)d_ws + 150994944);  // 25.2 MB
  unsigned short* X1   = (unsigned short*)((char*)d_ws + 176160768);  // 12.6 MB
  unsigned short* G2   = (unsigned short*)((char*)d_ws + 188743680);  // 12.6 MB
  unsigned short* WP   = (unsigned short*)((char*)d_ws + 201326592);  // 96 KB
  unsigned short* CMAT = (unsigned short*)((char*)d_ws + 201424896);  // 2.36 MB
  unsigned short* WA = WP;             // awh padded [288][64]
  unsigned short* WO = WP + 18432;     // awo [48][96]
  unsigned short* WI = WP + 23040;     // fwi padded [288][64]
  unsigned short* WF = WP + 41472;     // fwo padded [48][160]

  k_prep_w<<<960, 64, 0, stream>>>(awh, awo, fwi, fwo, fff, WP, CMAT);
  // FSAS: hidden = W_h * LN1(x)  [LN fused]
  k_gemm<288, 48, 64, 1, 0><<<2048, 256, 0, stream>>>(WA, x, nullptr, n1w,
                                                      n1b, nullptr, HID);
  // q,k fused patch conv -> U ; v dwconv -> QKV (merged kernel)
  k_fsas_fused<<<2 * 192 * 32, 256, 0, stream>>>(HID, adw, U, QKV);
  // x1 = x + W_o*(LN(u)*v); y = W_in*LN(x1)  [merged, x1 tile in LDS]
  k_gemm23<<<2048, 256, 0, stream>>>(WO, WI, U, QKV, anw, anb, n2w, n2b, x,
                                     X1);
  // spectral filter (MFMA circulant, z in LDS) + dwconv + GELU gate
  k_dffn_mfma<<<2 * 144 * 32, 256, 0, stream>>>(QKV, CMAT, fdw, U, G2);
  // out = x1 + W_out * g  (g split U/G2), fp32 output
  k_gemm<48, 144, 160, 0, 2><<<2048, 256, 0, stream>>>(WF, U, G2, nullptr,
                                                       nullptr, X1,
                                                       (float*)d_out);
}